// Round 10
// baseline (297.546 us; speedup 1.0000x reference)
//
#include <hip/hip_runtime.h>
#include <hip/hip_bf16.h>
#include <cmath>

#define N_NODESC 20000
#define E_RAW    320000
#define E_TOTC   340000   // + self loops
#define HEADSC   4
#define FC       256      // HEADS*HID
#define NEG_SLOPE 0.2f

typedef __attribute__((ext_vector_type(8))) short short8v;   // 8 bf16 = 4 VGPR
typedef __attribute__((ext_vector_type(4))) float f32x4;

__device__ __forceinline__ int dstOf(const int* ei, int e) {
  return (e < E_RAW) ? ei[E_RAW + e] : (e - E_RAW);
}
__device__ __forceinline__ int srcOf(const int* ei, int e) {
  return (e < E_RAW) ? ei[e] : (e - E_RAW);
}
__device__ __forceinline__ float lrelu(float v) { return v > 0.f ? v : NEG_SLOPE * v; }

__device__ __forceinline__ unsigned short f2bf(float f) {
  __hip_bfloat16 h = __float2bfloat16(f);           // RN
  return reinterpret_cast<unsigned short&>(h);
}
__device__ __forceinline__ float bf2f(unsigned short u) {
  return __uint_as_float(((unsigned int)u) << 16);
}

// ---------- prep: elementwise f32 -> (bf16 hi, bf16 lo) --------------------
__global__ void prep_split(const float* __restrict__ in, unsigned short* __restrict__ hi,
                           unsigned short* __restrict__ lo, int n) {
  int i = blockIdx.x * 256 + threadIdx.x;
  if (i >= n) return;
  float v = in[i];
  unsigned short h = f2bf(v);
  hi[i] = h;
  lo[i] = f2bf(v - bf2f(h));
}

// ---------- prep: W[K][256] f32 -> WhiT/WloT[256][K] bf16 (transposed) -----
template<int K>
__global__ void prep_wt(const float* __restrict__ W, unsigned short* __restrict__ hiT,
                        unsigned short* __restrict__ loT) {
  int idx = blockIdx.x * 256 + threadIdx.x;        // total 256*K
  if (idx >= 256 * K) return;
  int c = idx / K, k = idx - c * K;                // k fastest -> coalesced writes
  float v = W[(long)k * FC + c];
  unsigned short h = f2bf(v);
  hiT[(long)c * K + k] = h;
  loT[(long)c * K + k] = f2bf(v - bf2f(h));
}

// ---------- MFMA GEMM: hb[N][256] = A@W via 3-term bf16 compensation -------
// block = 256 thr = 4 waves; 16 rows/block; wave w covers cols w*64..w*64+63
// (4 tiles of 16x16). K-loop step 32. A row-major bf16 hi/lo; W transposed.
template<int K>
__global__ void __launch_bounds__(256) mfma_gemm(
    const unsigned short* __restrict__ Ahi, const unsigned short* __restrict__ Alo,
    const unsigned short* __restrict__ WhiT, const unsigned short* __restrict__ WloT,
    unsigned short* __restrict__ hb) {
  const int t = threadIdx.x;
  const int w = t >> 6, l = t & 63;
  const int n0 = blockIdx.x * 16;                  // 1250 blocks exact
  const int r16 = l & 15;                          // A-row / B-col within tile
  const int kq = l >> 4;                           // k-subgroup (x8)
  const int col0 = w * 64;
  f32x4 acc[4];
#pragma unroll
  for (int ct = 0; ct < 4; ++ct) acc[ct] = f32x4{0.f, 0.f, 0.f, 0.f};
  const long arow = (long)(n0 + r16) * K;
  for (int ks = 0; ks < K; ks += 32) {
    const int kb = ks + kq * 8;
    short8v aHi = *(const short8v*)(Ahi + arow + kb);
    short8v aLo = *(const short8v*)(Alo + arow + kb);
#pragma unroll
    for (int ct = 0; ct < 4; ++ct) {
      const long wrow = (long)(col0 + ct * 16 + r16) * K + kb;
      short8v wHi = *(const short8v*)(WhiT + wrow);
      short8v wLo = *(const short8v*)(WloT + wrow);
      acc[ct] = __builtin_amdgcn_mfma_f32_16x16x32_bf16(aHi, wHi, acc[ct], 0, 0, 0);
      acc[ct] = __builtin_amdgcn_mfma_f32_16x16x32_bf16(aHi, wLo, acc[ct], 0, 0, 0);
      acc[ct] = __builtin_amdgcn_mfma_f32_16x16x32_bf16(aLo, wHi, acc[ct], 0, 0, 0);
    }
  }
  // C/D: col = lane&15 (within tile), row = (lane>>4)*4 + reg
#pragma unroll
  for (int ct = 0; ct < 4; ++ct) {
    int c = col0 + ct * 16 + r16;
#pragma unroll
    for (int j = 0; j < 4; ++j) {
      int r = n0 + kq * 4 + j;
      hb[(long)r * FC + c] = f2bf(acc[ct][j]);
    }
  }
}

// ------------- per-node alpha_src/alpha_dst from bf16 hfeat ----------------
__global__ void alpha_kernel(const unsigned short* __restrict__ hb,
                             const float* __restrict__ a_src, const float* __restrict__ a_dst,
                             float* __restrict__ as, float* __restrict__ ad) {
  const int n = blockIdx.x;
  const int t = threadIdx.x;            // 256: head = t>>6, c = t&63
  float hv = bf2f(hb[(long)n * FC + t]);
  float vs = hv * a_src[t];
  float vd = hv * a_dst[t];
  for (int off = 32; off; off >>= 1) {
    vs += __shfl_down(vs, off, 64);
    vd += __shfl_down(vd, off, 64);
  }
  if ((t & 63) == 0) {
    as[n * HEADSC + (t >> 6)] = vs;
    ad[n * HEADSC + (t >> 6)] = vd;
  }
}

// ------------- layer3 projection: h3[n] = act[n,:] . W3, + alphas ----------
__global__ void gemm3_kernel(const unsigned short* __restrict__ act_hi,
                             const unsigned short* __restrict__ act_lo,
                             const float* __restrict__ W3,
                             const float* __restrict__ asc, const float* __restrict__ adc,
                             float* __restrict__ h3, float* __restrict__ as,
                             float* __restrict__ ad) {
  const int n = blockIdx.x;
  const int t = threadIdx.x;            // 256
  float a = bf2f(act_hi[(long)n * FC + t]) + bf2f(act_lo[(long)n * FC + t]);
  float v = a * W3[t];
  for (int off = 32; off; off >>= 1) v += __shfl_down(v, off, 64);
  __shared__ float red[4];
  if ((t & 63) == 0) red[t >> 6] = v;
  __syncthreads();
  if (t == 0) {
    float s = red[0] + red[1] + red[2] + red[3];
    h3[n] = s;
    as[n] = s * asc[0];
    ad[n] = s * adc[0];
  }
}

// ----------------------------- CSR build -----------------------------------
__global__ void zero_deg(int* __restrict__ deg) {
  int i = blockIdx.x * 256 + threadIdx.x;
  if (i < N_NODESC) deg[i] = 0;
}

__global__ void deg_count(const int* __restrict__ ei, int* __restrict__ deg) {
  int e = blockIdx.x * 256 + threadIdx.x;
  if (e >= E_TOTC) return;
  atomicAdd(&deg[dstOf(ei, e)], 1);
}

__global__ void scan_kernel(const int* __restrict__ deg, int* __restrict__ row_ptr,
                            int* __restrict__ cursor) {
  __shared__ int partial[1024];
  const int t = threadIdx.x;                       // 1024 threads, single block
  const int PER = (N_NODESC + 1023) / 1024;        // 20
  const int base = t * PER;
  int s = 0;
  for (int i = 0; i < PER; ++i) {
    int idx = base + i;
    if (idx < N_NODESC) s += deg[idx];
  }
  partial[t] = s;
  __syncthreads();
  for (int off = 1; off < 1024; off <<= 1) {
    int v = (t >= off) ? partial[t - off] : 0;
    __syncthreads();
    partial[t] += v;
    __syncthreads();
  }
  int run = (t == 0) ? 0 : partial[t - 1];
  for (int i = 0; i < PER; ++i) {
    int idx = base + i;
    if (idx < N_NODESC) {
      row_ptr[idx] = run;
      cursor[idx]  = run;
      run += deg[idx];
    }
  }
  if (t == 1023) row_ptr[N_NODESC] = run;          // = E_TOTC
}

__global__ void fill_kernel(const int* __restrict__ ei, int* __restrict__ cursor,
                            int* __restrict__ col_src) {
  int e = blockIdx.x * 256 + threadIdx.x;
  if (e >= E_TOTC) return;
  int d = dstOf(ei, e);
  int pos = atomicAdd(&cursor[d], 1);
  col_src[pos] = srcOf(ei, e);
}

// --- softmax, H=4: one WAVE per node; lanes stride edges; xor-shuffle reduce
__global__ void softmax4_kernel(const int* __restrict__ row_ptr, const int* __restrict__ col_src,
                                const float4* __restrict__ as4, const float4* __restrict__ ad4,
                                float4* __restrict__ ebuf4, float4* __restrict__ denom4) {
  const int w = threadIdx.x >> 6, l = threadIdx.x & 63;
  const int n = blockIdx.x * 4 + w;
  if (n >= N_NODESC) return;
  const int j0 = row_ptr[n], j1 = row_ptr[n + 1];
  const float4 adv = ad4[n];
  float4 mx = float4{-INFINITY, -INFINITY, -INFINITY, -INFINITY};
  for (int j = j0 + l; j < j1; j += 64) {
    float4 a = as4[col_src[j]];
    float4 v;
    v.x = lrelu(a.x + adv.x); v.y = lrelu(a.y + adv.y);
    v.z = lrelu(a.z + adv.z); v.w = lrelu(a.w + adv.w);
    ebuf4[j] = v;
    mx.x = fmaxf(mx.x, v.x); mx.y = fmaxf(mx.y, v.y);
    mx.z = fmaxf(mx.z, v.z); mx.w = fmaxf(mx.w, v.w);
  }
  for (int off = 32; off; off >>= 1) {
    mx.x = fmaxf(mx.x, __shfl_xor(mx.x, off, 64));
    mx.y = fmaxf(mx.y, __shfl_xor(mx.y, off, 64));
    mx.z = fmaxf(mx.z, __shfl_xor(mx.z, off, 64));
    mx.w = fmaxf(mx.w, __shfl_xor(mx.w, off, 64));
  }
  float4 sm = float4{0.f, 0.f, 0.f, 0.f};
  for (int j = j0 + l; j < j1; j += 64) {
    float4 v = ebuf4[j];
    float4 e;
    e.x = expf(v.x - mx.x); e.y = expf(v.y - mx.y);
    e.z = expf(v.z - mx.z); e.w = expf(v.w - mx.w);
    ebuf4[j] = e;
    sm.x += e.x; sm.y += e.y; sm.z += e.z; sm.w += e.w;
  }
  for (int off = 32; off; off >>= 1) {
    sm.x += __shfl_xor(sm.x, off, 64);
    sm.y += __shfl_xor(sm.y, off, 64);
    sm.z += __shfl_xor(sm.z, off, 64);
    sm.w += __shfl_xor(sm.w, off, 64);
  }
  if (l == 0)
    denom4[n] = float4{1.f / sm.x, 1.f / sm.y, 1.f / sm.z, 1.f / sm.w};
}

// --- softmax, H=1: one wave per node ---
__global__ void softmax1_kernel(const int* __restrict__ row_ptr, const int* __restrict__ col_src,
                                const float* __restrict__ as, const float* __restrict__ ad,
                                float* __restrict__ ebuf, float* __restrict__ denom) {
  const int w = threadIdx.x >> 6, l = threadIdx.x & 63;
  const int n = blockIdx.x * 4 + w;
  if (n >= N_NODESC) return;
  const int j0 = row_ptr[n], j1 = row_ptr[n + 1];
  const float adv = ad[n];
  float mx = -INFINITY;
  for (int j = j0 + l; j < j1; j += 64) {
    float v = lrelu(as[col_src[j]] + adv);
    ebuf[j] = v;
    mx = fmaxf(mx, v);
  }
  for (int off = 32; off; off >>= 1) mx = fmaxf(mx, __shfl_xor(mx, off, 64));
  float sm = 0.f;
  for (int j = j0 + l; j < j1; j += 64) {
    float e = expf(ebuf[j] - mx);
    ebuf[j] = e;
    sm += e;
  }
  for (int off = 32; off; off >>= 1) sm += __shfl_xor(sm, off, 64);
  if (l == 0) denom[n] = 1.f / sm;
}

// --- aggregation: 1 node/block, 128 thr, thread = 2 channels; out = hi/lo bf16
template<bool ELU>
__global__ void agg_kernel(const int* __restrict__ row_ptr, const int* __restrict__ col_src,
                           const float* __restrict__ ebuf, const float* __restrict__ denom,
                           const unsigned short* __restrict__ hb, const float* __restrict__ b,
                           unsigned short* __restrict__ out_hi, unsigned short* __restrict__ out_lo) {
  const int d = blockIdx.x;
  const int t = threadIdx.x;                       // 0..127, channel pair 2t,2t+1
  const int h = t >> 5;
  const int j0 = row_ptr[d], j1 = row_ptr[d + 1];
  const ushort2* hb2 = (const ushort2*)hb;         // 128 pairs per row
  float a0 = 0.f, a1 = 0.f;
  int j = j0;
  for (; j + 8 <= j1; j += 8) {
    int     s[8];
    ushort2 v[8];
    float   w[8];
#pragma unroll
    for (int u = 0; u < 8; ++u) s[u] = col_src[j + u];
#pragma unroll
    for (int u = 0; u < 8; ++u) v[u] = hb2[(long)s[u] * 128 + t];
#pragma unroll
    for (int u = 0; u < 8; ++u) w[u] = ebuf[(j + u) * HEADSC + h];
#pragma unroll
    for (int u = 0; u < 8; ++u) {
      a0 = fmaf(w[u], bf2f(v[u].x), a0);
      a1 = fmaf(w[u], bf2f(v[u].y), a1);
    }
  }
  for (; j < j1; ++j) {
    ushort2 v = hb2[(long)col_src[j] * 128 + t];
    float w = ebuf[j * HEADSC + h];
    a0 = fmaf(w, bf2f(v.x), a0);
    a1 = fmaf(w, bf2f(v.y), a1);
  }
  float dn = denom[d * HEADSC + h];
  float o0 = a0 * dn + b[2 * t];
  float o1 = a1 * dn + b[2 * t + 1];
  if (ELU) {
    o0 = o0 > 0.f ? o0 : expm1f(o0);
    o1 = o1 > 0.f ? o1 : expm1f(o1);
  }
  ushort2 hi, lo;
  hi.x = f2bf(o0); lo.x = f2bf(o0 - bf2f(hi.x));
  hi.y = f2bf(o1); lo.y = f2bf(o1 - bf2f(hi.y));
  ((ushort2*)out_hi)[(long)d * 128 + t] = hi;
  ((ushort2*)out_lo)[(long)d * 128 + t] = lo;
}

// ------------- layer3 aggregation: wave per node, scalar -------------------
__global__ void agg3_kernel(const int* __restrict__ row_ptr, const int* __restrict__ col_src,
                            const float* __restrict__ ebuf, const float* __restrict__ denom,
                            const float* __restrict__ h3, const float* __restrict__ b3,
                            float* __restrict__ out) {
  const int wv = threadIdx.x >> 6;                 // 4 waves/block
  const int l  = threadIdx.x & 63;
  const int d  = blockIdx.x * 4 + wv;
  if (d >= N_NODESC) return;
  const int j0 = row_ptr[d], j1 = row_ptr[d + 1];
  float acc = 0.f;
  for (int j = j0 + l; j < j1; j += 64)
    acc = fmaf(ebuf[j], h3[col_src[j]], acc);
  for (int off = 32; off; off >>= 1) acc += __shfl_down(acc, off, 64);
  if (l == 0) out[d] = acc * denom[d] + b3[0];
}

extern "C" void kernel_launch(void* const* d_in, const int* in_sizes, int n_in,
                              void* d_out, int out_size, void* d_ws, size_t ws_size,
                              hipStream_t stream) {
  const float* x    = (const float*)d_in[0];
  const int*   ei   = (const int*)d_in[1];
  const float* W1   = (const float*)d_in[2];
  const float* as1  = (const float*)d_in[3];
  const float* ad1  = (const float*)d_in[4];
  const float* b1   = (const float*)d_in[5];
  const float* W2   = (const float*)d_in[6];
  const float* as2  = (const float*)d_in[7];
  const float* ad2  = (const float*)d_in[8];
  const float* b2   = (const float*)d_in[9];
  const float* W3   = (const float*)d_in[10];
  const float* as3  = (const float*)d_in[11];
  const float* ad3  = (const float*)d_in[12];
  const float* b3   = (const float*)d_in[13];
  float* out = (float*)d_out;

  float* ws = (float*)d_ws;
  size_t off = 0;
  float* wAs   = ws + off; off += (size_t)N_NODESC * HEADSC;
  float* wAd   = ws + off; off += (size_t)N_NODESC * HEADSC;
  float* denom = ws + off; off += (size_t)N_NODESC * HEADSC;
  float* ebuf  = ws + off; off += (size_t)E_TOTC * HEADSC;
  float* h3    = ws + off; off += N_NODESC;
  int* deg     = (int*)(ws + off); off += N_NODESC;
  int* row_ptr = (int*)(ws + off); off += N_NODESC + 1;
  int* cursor  = (int*)(ws + off); off += N_NODESC;
  int* col_src = (int*)(ws + off); off += E_TOTC;
  off = (off + 3) & ~(size_t)3;                     // 16B align for bf16 vectors
  unsigned short* hb     = (unsigned short*)(ws + off); off += (size_t)N_NODESC * 128;
  unsigned short* act_hi = (unsigned short*)(ws + off); off += (size_t)N_NODESC * 128;
  unsigned short* act_lo = (unsigned short*)(ws + off); off += (size_t)N_NODESC * 128;
  unsigned short* xhi    = (unsigned short*)(ws + off); off += (size_t)N_NODESC * 64;
  unsigned short* xlo    = (unsigned short*)(ws + off); off += (size_t)N_NODESC * 64;
  unsigned short* WhiT   = (unsigned short*)(ws + off); off += 32768;
  unsigned short* WloT   = (unsigned short*)(ws + off); off += 32768;

  const int gridE  = (E_TOTC + 255) / 256;
  const int gridN  = (N_NODESC + 255) / 256;
  const int gridN4 = (N_NODESC + 3) / 4;
  const int gemmG  = N_NODESC / 16;       // 1250, exact

  // ---------------- CSR build + x split ------------------------------------
  zero_deg<<<gridN, 256, 0, stream>>>(deg);
  deg_count<<<gridE, 256, 0, stream>>>(ei, deg);
  scan_kernel<<<1, 1024, 0, stream>>>(deg, row_ptr, cursor);
  fill_kernel<<<gridE, 256, 0, stream>>>(ei, cursor, col_src);
  prep_split<<<(N_NODESC * 128 + 255) / 256, 256, 0, stream>>>(x, xhi, xlo, N_NODESC * 128);

  // ---------------- layer 1 (K=128) ----------------
  prep_wt<128><<<(256 * 128 + 255) / 256, 256, 0, stream>>>(W1, WhiT, WloT);
  mfma_gemm<128><<<gemmG, 256, 0, stream>>>(xhi, xlo, WhiT, WloT, hb);
  alpha_kernel<<<N_NODESC, 256, 0, stream>>>(hb, as1, ad1, wAs, wAd);
  softmax4_kernel<<<gridN4, 256, 0, stream>>>(row_ptr, col_src, (const float4*)wAs,
                                              (const float4*)wAd, (float4*)ebuf, (float4*)denom);
  agg_kernel<true><<<N_NODESC, 128, 0, stream>>>(row_ptr, col_src, ebuf, denom, hb, b1,
                                                 act_hi, act_lo);

  // ---------------- layer 2 (K=256) ----------------
  prep_wt<256><<<(256 * 256 + 255) / 256, 256, 0, stream>>>(W2, WhiT, WloT);
  mfma_gemm<256><<<gemmG, 256, 0, stream>>>(act_hi, act_lo, WhiT, WloT, hb);
  alpha_kernel<<<N_NODESC, 256, 0, stream>>>(hb, as2, ad2, wAs, wAd);
  softmax4_kernel<<<gridN4, 256, 0, stream>>>(row_ptr, col_src, (const float4*)wAs,
                                              (const float4*)wAd, (float4*)ebuf, (float4*)denom);
  agg_kernel<true><<<N_NODESC, 128, 0, stream>>>(row_ptr, col_src, ebuf, denom, hb, b2,
                                                 act_hi, act_lo);

  // ---------------- layer 3 (heads=1, out=1) ----------------
  gemm3_kernel<<<N_NODESC, 256, 0, stream>>>(act_hi, act_lo, W3, as3, ad3, h3, wAs, wAd);
  softmax1_kernel<<<gridN4, 256, 0, stream>>>(row_ptr, col_src, wAs, wAd, ebuf, denom);
  agg3_kernel<<<gridN4, 256, 0, stream>>>(row_ptr, col_src, ebuf, denom, h3, b3, out);
}

// Round 11
// 260.329 us; speedup vs baseline: 1.1430x; 1.1430x over previous
//
#include <hip/hip_runtime.h>
#include <hip/hip_bf16.h>
#include <cmath>

#define N_NODESC 20000
#define E_RAW    320000
#define E_TOTC   340000   // + self loops
#define HEADSC   4
#define FC       256      // HEADS*HID
#define NEG_SLOPE 0.2f

typedef __attribute__((ext_vector_type(8))) short short8v;   // 8 bf16 = 4 VGPR
typedef __attribute__((ext_vector_type(4))) float f32x4;

__device__ __forceinline__ int dstOf(const int* ei, int e) {
  return (e < E_RAW) ? ei[E_RAW + e] : (e - E_RAW);
}
__device__ __forceinline__ int srcOf(const int* ei, int e) {
  return (e < E_RAW) ? ei[e] : (e - E_RAW);
}
__device__ __forceinline__ float lrelu(float v) { return v > 0.f ? v : NEG_SLOPE * v; }

__device__ __forceinline__ unsigned short f2bf(float f) {
  __hip_bfloat16 h = __float2bfloat16(f);           // RN
  return reinterpret_cast<unsigned short&>(h);
}
__device__ __forceinline__ float bf2f(unsigned short u) {
  return __uint_as_float(((unsigned int)u) << 16);
}

// ---------- prep: elementwise f32 -> (bf16 hi, bf16 lo) --------------------
__global__ void prep_split(const float* __restrict__ in, unsigned short* __restrict__ hi,
                           unsigned short* __restrict__ lo, int n) {
  int i = blockIdx.x * 256 + threadIdx.x;
  if (i >= n) return;
  float v = in[i];
  unsigned short h = f2bf(v);
  hi[i] = h;
  lo[i] = f2bf(v - bf2f(h));
}

// ---------- prep: W[K][256] f32 -> WhiT/WloT[256][K] bf16 (transposed) -----
template<int K>
__global__ void prep_wt(const float* __restrict__ W, unsigned short* __restrict__ hiT,
                        unsigned short* __restrict__ loT) {
  int idx = blockIdx.x * 256 + threadIdx.x;        // total 256*K
  if (idx >= 256 * K) return;
  int c = idx / K, k = idx - c * K;                // k fastest -> coalesced writes
  float v = W[(long)k * FC + c];
  unsigned short h = f2bf(v);
  hiT[(long)c * K + k] = h;
  loT[(long)c * K + k] = f2bf(v - bf2f(h));
}

// ---------- MFMA GEMM + fused alpha: hb[N][256] = A@W (3-term bf16 comp) ---
// block = 256 thr = 4 waves; 64 rows/block (4 row-tiles of 16).
// Wave w covers cols w*64..w*64+63 == HEAD w (4 col-tiles of 16).
// acc[rt][ct]: 48 MFMAs per 16 loads per k-step (latency-hiding by intensity).
template<int K>
__global__ void __launch_bounds__(256) mfma_gemm(
    const unsigned short* __restrict__ Ahi, const unsigned short* __restrict__ Alo,
    const unsigned short* __restrict__ WhiT, const unsigned short* __restrict__ WloT,
    const float* __restrict__ a_src, const float* __restrict__ a_dst,
    unsigned short* __restrict__ hb, float* __restrict__ as, float* __restrict__ ad) {
  __shared__ float asred[64][4];
  __shared__ float adred[64][4];
  const int t = threadIdx.x;
  const int w = t >> 6, l = t & 63;
  const int n0 = blockIdx.x * 64;                  // 313 blocks, last partial
  const int r16 = l & 15;                          // row/col within 16-tile
  const int kq = l >> 4;                           // k-subgroup (x8)
  const int col0 = w * 64;

  f32x4 acc[4][4];
#pragma unroll
  for (int rt = 0; rt < 4; ++rt)
#pragma unroll
    for (int ct = 0; ct < 4; ++ct) acc[rt][ct] = f32x4{0.f, 0.f, 0.f, 0.f};

  long arow[4];
#pragma unroll
  for (int rt = 0; rt < 4; ++rt) {
    int r = n0 + rt * 16 + r16;
    if (r >= N_NODESC) r = N_NODESC - 1;           // clamp loads; stores guarded
    arow[rt] = (long)r * K;
  }

  for (int ks = 0; ks < K; ks += 32) {
    const int kb = ks + kq * 8;
    short8v aHi[4], aLo[4];
#pragma unroll
    for (int rt = 0; rt < 4; ++rt) {
      aHi[rt] = *(const short8v*)(Ahi + arow[rt] + kb);
      aLo[rt] = *(const short8v*)(Alo + arow[rt] + kb);
    }
#pragma unroll
    for (int ct = 0; ct < 4; ++ct) {
      const long wrow = (long)(col0 + ct * 16 + r16) * K + kb;
      short8v wHi = *(const short8v*)(WhiT + wrow);
      short8v wLo = *(const short8v*)(WloT + wrow);
#pragma unroll
      for (int rt = 0; rt < 4; ++rt) {
        acc[rt][ct] = __builtin_amdgcn_mfma_f32_16x16x32_bf16(aHi[rt], wHi, acc[rt][ct], 0, 0, 0);
        acc[rt][ct] = __builtin_amdgcn_mfma_f32_16x16x32_bf16(aHi[rt], wLo, acc[rt][ct], 0, 0, 0);
        acc[rt][ct] = __builtin_amdgcn_mfma_f32_16x16x32_bf16(aLo[rt], wHi, acc[rt][ct], 0, 0, 0);
      }
    }
  }

  // epilogue: hb store + fused alpha (wave w == head w)
  float asv[4], adv[4];
#pragma unroll
  for (int ct = 0; ct < 4; ++ct) {
    int c = col0 + ct * 16 + r16;
    asv[ct] = a_src[c];
    adv[ct] = a_dst[c];
  }
#pragma unroll
  for (int rt = 0; rt < 4; ++rt) {
#pragma unroll
    for (int j = 0; j < 4; ++j) {
      const int r = rt * 16 + kq * 4 + j;          // row within block
      const int g = n0 + r;
      if (g < N_NODESC) {
#pragma unroll
        for (int ct = 0; ct < 4; ++ct)
          hb[(long)g * FC + col0 + ct * 16 + r16] = f2bf(acc[rt][ct][j]);
      }
      float ps = acc[rt][0][j] * asv[0] + acc[rt][1][j] * asv[1]
               + acc[rt][2][j] * asv[2] + acc[rt][3][j] * asv[3];
      float pd = acc[rt][0][j] * adv[0] + acc[rt][1][j] * adv[1]
               + acc[rt][2][j] * adv[2] + acc[rt][3][j] * adv[3];
      for (int off = 8; off; off >>= 1) {
        ps += __shfl_down(ps, off, 16);
        pd += __shfl_down(pd, off, 16);
      }
      if (r16 == 0) {
        asred[r][w] = ps;
        adred[r][w] = pd;
      }
    }
  }
  __syncthreads();
  {
    const int rr = t >> 2, hh = t & 3;
    const int g = n0 + rr;
    if (g < N_NODESC) {
      as[(long)g * HEADSC + hh] = asred[rr][hh];
      ad[(long)g * HEADSC + hh] = adred[rr][hh];
    }
  }
}

// ------------- layer3 projection: h3[n] = act[n,:] . W3, + alphas ----------
__global__ void gemm3_kernel(const unsigned short* __restrict__ act_hi,
                             const unsigned short* __restrict__ act_lo,
                             const float* __restrict__ W3,
                             const float* __restrict__ asc, const float* __restrict__ adc,
                             float* __restrict__ h3, float* __restrict__ as,
                             float* __restrict__ ad) {
  const int n = blockIdx.x;
  const int t = threadIdx.x;            // 256
  float a = bf2f(act_hi[(long)n * FC + t]) + bf2f(act_lo[(long)n * FC + t]);
  float v = a * W3[t];
  for (int off = 32; off; off >>= 1) v += __shfl_down(v, off, 64);
  __shared__ float red[4];
  if ((t & 63) == 0) red[t >> 6] = v;
  __syncthreads();
  if (t == 0) {
    float s = red[0] + red[1] + red[2] + red[3];
    h3[n] = s;
    as[n] = s * asc[0];
    ad[n] = s * adc[0];
  }
}

// ----------------------------- CSR build -----------------------------------
__global__ void zero_deg(int* __restrict__ deg) {
  int i = blockIdx.x * 256 + threadIdx.x;
  if (i < N_NODESC) deg[i] = 0;
}

__global__ void deg_count(const int* __restrict__ ei, int* __restrict__ deg) {
  int e = blockIdx.x * 256 + threadIdx.x;
  if (e >= E_TOTC) return;
  atomicAdd(&deg[dstOf(ei, e)], 1);
}

__global__ void scan_kernel(const int* __restrict__ deg, int* __restrict__ row_ptr,
                            int* __restrict__ cursor) {
  __shared__ int partial[1024];
  const int t = threadIdx.x;                       // 1024 threads, single block
  const int PER = (N_NODESC + 1023) / 1024;        // 20
  const int base = t * PER;
  int s = 0;
  for (int i = 0; i < PER; ++i) {
    int idx = base + i;
    if (idx < N_NODESC) s += deg[idx];
  }
  partial[t] = s;
  __syncthreads();
  for (int off = 1; off < 1024; off <<= 1) {
    int v = (t >= off) ? partial[t - off] : 0;
    __syncthreads();
    partial[t] += v;
    __syncthreads();
  }
  int run = (t == 0) ? 0 : partial[t - 1];
  for (int i = 0; i < PER; ++i) {
    int idx = base + i;
    if (idx < N_NODESC) {
      row_ptr[idx] = run;
      cursor[idx]  = run;
      run += deg[idx];
    }
  }
  if (t == 1023) row_ptr[N_NODESC] = run;          // = E_TOTC
}

__global__ void fill_kernel(const int* __restrict__ ei, int* __restrict__ cursor,
                            int* __restrict__ col_src) {
  int e = blockIdx.x * 256 + threadIdx.x;
  if (e >= E_TOTC) return;
  int d = dstOf(ei, e);
  int pos = atomicAdd(&cursor[d], 1);
  col_src[pos] = srcOf(ei, e);
}

// --- softmax, H=4: one WAVE per node; lanes stride edges; xor-shuffle reduce
__global__ void softmax4_kernel(const int* __restrict__ row_ptr, const int* __restrict__ col_src,
                                const float4* __restrict__ as4, const float4* __restrict__ ad4,
                                float4* __restrict__ ebuf4, float4* __restrict__ denom4) {
  const int w = threadIdx.x >> 6, l = threadIdx.x & 63;
  const int n = blockIdx.x * 4 + w;
  if (n >= N_NODESC) return;
  const int j0 = row_ptr[n], j1 = row_ptr[n + 1];
  const float4 adv = ad4[n];
  float4 mx = float4{-INFINITY, -INFINITY, -INFINITY, -INFINITY};
  for (int j = j0 + l; j < j1; j += 64) {
    float4 a = as4[col_src[j]];
    float4 v;
    v.x = lrelu(a.x + adv.x); v.y = lrelu(a.y + adv.y);
    v.z = lrelu(a.z + adv.z); v.w = lrelu(a.w + adv.w);
    ebuf4[j] = v;
    mx.x = fmaxf(mx.x, v.x); mx.y = fmaxf(mx.y, v.y);
    mx.z = fmaxf(mx.z, v.z); mx.w = fmaxf(mx.w, v.w);
  }
  for (int off = 32; off; off >>= 1) {
    mx.x = fmaxf(mx.x, __shfl_xor(mx.x, off, 64));
    mx.y = fmaxf(mx.y, __shfl_xor(mx.y, off, 64));
    mx.z = fmaxf(mx.z, __shfl_xor(mx.z, off, 64));
    mx.w = fmaxf(mx.w, __shfl_xor(mx.w, off, 64));
  }
  float4 sm = float4{0.f, 0.f, 0.f, 0.f};
  for (int j = j0 + l; j < j1; j += 64) {
    float4 v = ebuf4[j];
    float4 e;
    e.x = expf(v.x - mx.x); e.y = expf(v.y - mx.y);
    e.z = expf(v.z - mx.z); e.w = expf(v.w - mx.w);
    ebuf4[j] = e;
    sm.x += e.x; sm.y += e.y; sm.z += e.z; sm.w += e.w;
  }
  for (int off = 32; off; off >>= 1) {
    sm.x += __shfl_xor(sm.x, off, 64);
    sm.y += __shfl_xor(sm.y, off, 64);
    sm.z += __shfl_xor(sm.z, off, 64);
    sm.w += __shfl_xor(sm.w, off, 64);
  }
  if (l == 0)
    denom4[n] = float4{1.f / sm.x, 1.f / sm.y, 1.f / sm.z, 1.f / sm.w};
}

// --- softmax, H=1: one wave per node ---
__global__ void softmax1_kernel(const int* __restrict__ row_ptr, const int* __restrict__ col_src,
                                const float* __restrict__ as, const float* __restrict__ ad,
                                float* __restrict__ ebuf, float* __restrict__ denom) {
  const int w = threadIdx.x >> 6, l = threadIdx.x & 63;
  const int n = blockIdx.x * 4 + w;
  if (n >= N_NODESC) return;
  const int j0 = row_ptr[n], j1 = row_ptr[n + 1];
  const float adv = ad[n];
  float mx = -INFINITY;
  for (int j = j0 + l; j < j1; j += 64) {
    float v = lrelu(as[col_src[j]] + adv);
    ebuf[j] = v;
    mx = fmaxf(mx, v);
  }
  for (int off = 32; off; off >>= 1) mx = fmaxf(mx, __shfl_xor(mx, off, 64));
  float sm = 0.f;
  for (int j = j0 + l; j < j1; j += 64) {
    float e = expf(ebuf[j] - mx);
    ebuf[j] = e;
    sm += e;
  }
  for (int off = 32; off; off >>= 1) sm += __shfl_xor(sm, off, 64);
  if (l == 0) denom[n] = 1.f / sm;
}

// --- aggregation: 1 node/block, 128 thr, thread = 2 channels; out = hi/lo bf16
template<bool ELU>
__global__ void agg_kernel(const int* __restrict__ row_ptr, const int* __restrict__ col_src,
                           const float* __restrict__ ebuf, const float* __restrict__ denom,
                           const unsigned short* __restrict__ hb, const float* __restrict__ b,
                           unsigned short* __restrict__ out_hi, unsigned short* __restrict__ out_lo) {
  const int d = blockIdx.x;
  const int t = threadIdx.x;                       // 0..127, channel pair 2t,2t+1
  const int h = t >> 5;
  const int j0 = row_ptr[d], j1 = row_ptr[d + 1];
  const ushort2* hb2 = (const ushort2*)hb;         // 128 pairs per row
  float a0 = 0.f, a1 = 0.f;
  int j = j0;
  for (; j + 8 <= j1; j += 8) {
    int     s[8];
    ushort2 v[8];
    float   w[8];
#pragma unroll
    for (int u = 0; u < 8; ++u) s[u] = col_src[j + u];
#pragma unroll
    for (int u = 0; u < 8; ++u) v[u] = hb2[(long)s[u] * 128 + t];
#pragma unroll
    for (int u = 0; u < 8; ++u) w[u] = ebuf[(j + u) * HEADSC + h];
#pragma unroll
    for (int u = 0; u < 8; ++u) {
      a0 = fmaf(w[u], bf2f(v[u].x), a0);
      a1 = fmaf(w[u], bf2f(v[u].y), a1);
    }
  }
  for (; j < j1; ++j) {
    ushort2 v = hb2[(long)col_src[j] * 128 + t];
    float w = ebuf[j * HEADSC + h];
    a0 = fmaf(w, bf2f(v.x), a0);
    a1 = fmaf(w, bf2f(v.y), a1);
  }
  float dn = denom[d * HEADSC + h];
  float o0 = a0 * dn + b[2 * t];
  float o1 = a1 * dn + b[2 * t + 1];
  if (ELU) {
    o0 = o0 > 0.f ? o0 : expm1f(o0);
    o1 = o1 > 0.f ? o1 : expm1f(o1);
  }
  ushort2 hi, lo;
  hi.x = f2bf(o0); lo.x = f2bf(o0 - bf2f(hi.x));
  hi.y = f2bf(o1); lo.y = f2bf(o1 - bf2f(hi.y));
  ((ushort2*)out_hi)[(long)d * 128 + t] = hi;
  ((ushort2*)out_lo)[(long)d * 128 + t] = lo;
}

// ------------- layer3 aggregation: wave per node, scalar -------------------
__global__ void agg3_kernel(const int* __restrict__ row_ptr, const int* __restrict__ col_src,
                            const float* __restrict__ ebuf, const float* __restrict__ denom,
                            const float* __restrict__ h3, const float* __restrict__ b3,
                            float* __restrict__ out) {
  const int wv = threadIdx.x >> 6;                 // 4 waves/block
  const int l  = threadIdx.x & 63;
  const int d  = blockIdx.x * 4 + wv;
  if (d >= N_NODESC) return;
  const int j0 = row_ptr[d], j1 = row_ptr[d + 1];
  float acc = 0.f;
  for (int j = j0 + l; j < j1; j += 64)
    acc = fmaf(ebuf[j], h3[col_src[j]], acc);
  for (int off = 32; off; off >>= 1) acc += __shfl_down(acc, off, 64);
  if (l == 0) out[d] = acc * denom[d] + b3[0];
}

extern "C" void kernel_launch(void* const* d_in, const int* in_sizes, int n_in,
                              void* d_out, int out_size, void* d_ws, size_t ws_size,
                              hipStream_t stream) {
  const float* x    = (const float*)d_in[0];
  const int*   ei   = (const int*)d_in[1];
  const float* W1   = (const float*)d_in[2];
  const float* as1  = (const float*)d_in[3];
  const float* ad1  = (const float*)d_in[4];
  const float* b1   = (const float*)d_in[5];
  const float* W2   = (const float*)d_in[6];
  const float* as2  = (const float*)d_in[7];
  const float* ad2  = (const float*)d_in[8];
  const float* b2   = (const float*)d_in[9];
  const float* W3   = (const float*)d_in[10];
  const float* as3  = (const float*)d_in[11];
  const float* ad3  = (const float*)d_in[12];
  const float* b3   = (const float*)d_in[13];
  float* out = (float*)d_out;

  float* ws = (float*)d_ws;
  size_t off = 0;
  float* wAs   = ws + off; off += (size_t)N_NODESC * HEADSC;
  float* wAd   = ws + off; off += (size_t)N_NODESC * HEADSC;
  float* denom = ws + off; off += (size_t)N_NODESC * HEADSC;
  float* ebuf  = ws + off; off += (size_t)E_TOTC * HEADSC;
  float* h3    = ws + off; off += N_NODESC;
  int* deg     = (int*)(ws + off); off += N_NODESC;
  int* row_ptr = (int*)(ws + off); off += N_NODESC + 1;
  int* cursor  = (int*)(ws + off); off += N_NODESC;
  int* col_src = (int*)(ws + off); off += E_TOTC;
  off = (off + 3) & ~(size_t)3;                     // 16B align for bf16 vectors
  unsigned short* hb     = (unsigned short*)(ws + off); off += (size_t)N_NODESC * 128;
  unsigned short* act_hi = (unsigned short*)(ws + off); off += (size_t)N_NODESC * 128;
  unsigned short* act_lo = (unsigned short*)(ws + off); off += (size_t)N_NODESC * 128;
  unsigned short* xhi    = (unsigned short*)(ws + off); off += (size_t)N_NODESC * 64;
  unsigned short* xlo    = (unsigned short*)(ws + off); off += (size_t)N_NODESC * 64;
  unsigned short* WhiT   = (unsigned short*)(ws + off); off += 32768;
  unsigned short* WloT   = (unsigned short*)(ws + off); off += 32768;

  const int gridE  = (E_TOTC + 255) / 256;
  const int gridN  = (N_NODESC + 255) / 256;
  const int gridN4 = (N_NODESC + 3) / 4;
  const int gemmG  = (N_NODESC + 63) / 64;          // 313

  // ---------------- CSR build + x split ------------------------------------
  zero_deg<<<gridN, 256, 0, stream>>>(deg);
  deg_count<<<gridE, 256, 0, stream>>>(ei, deg);
  scan_kernel<<<1, 1024, 0, stream>>>(deg, row_ptr, cursor);
  fill_kernel<<<gridE, 256, 0, stream>>>(ei, cursor, col_src);
  prep_split<<<(N_NODESC * 128 + 255) / 256, 256, 0, stream>>>(x, xhi, xlo, N_NODESC * 128);

  // ---------------- layer 1 (K=128) ----------------
  prep_wt<128><<<(256 * 128 + 255) / 256, 256, 0, stream>>>(W1, WhiT, WloT);
  mfma_gemm<128><<<gemmG, 256, 0, stream>>>(xhi, xlo, WhiT, WloT, as1, ad1, hb, wAs, wAd);
  softmax4_kernel<<<gridN4, 256, 0, stream>>>(row_ptr, col_src, (const float4*)wAs,
                                              (const float4*)wAd, (float4*)ebuf, (float4*)denom);
  agg_kernel<true><<<N_NODESC, 128, 0, stream>>>(row_ptr, col_src, ebuf, denom, hb, b1,
                                                 act_hi, act_lo);

  // ---------------- layer 2 (K=256) ----------------
  prep_wt<256><<<(256 * 256 + 255) / 256, 256, 0, stream>>>(W2, WhiT, WloT);
  mfma_gemm<256><<<gemmG, 256, 0, stream>>>(act_hi, act_lo, WhiT, WloT, as2, ad2, hb, wAs, wAd);
  softmax4_kernel<<<gridN4, 256, 0, stream>>>(row_ptr, col_src, (const float4*)wAs,
                                              (const float4*)wAd, (float4*)ebuf, (float4*)denom);
  agg_kernel<true><<<N_NODESC, 128, 0, stream>>>(row_ptr, col_src, ebuf, denom, hb, b2,
                                                 act_hi, act_lo);

  // ---------------- layer 3 (heads=1, out=1) ----------------
  gemm3_kernel<<<N_NODESC, 256, 0, stream>>>(act_hi, act_lo, W3, as3, ad3, h3, wAs, wAd);
  softmax1_kernel<<<gridN4, 256, 0, stream>>>(row_ptr, col_src, wAs, wAd, ebuf, denom);
  agg3_kernel<<<gridN4, 256, 0, stream>>>(row_ptr, col_src, ebuf, denom, h3, b3, out);
}

// Round 12
// 234.152 us; speedup vs baseline: 1.2707x; 1.1118x over previous
//
#include <hip/hip_runtime.h>
#include <hip/hip_bf16.h>
#include <cmath>

#define N_NODESC 20000
#define E_RAW    320000
#define E_TOTC   340000   // + self loops
#define HEADSC   4
#define FC       256      // HEADS*HID
#define NEG_SLOPE 0.2f
#define MAXD     512      // per-node edge cap held in LDS (true max deg ~50)

typedef __attribute__((ext_vector_type(8))) short short8v;   // 8 bf16 = 4 VGPR
typedef __attribute__((ext_vector_type(4))) float f32x4;

__device__ __forceinline__ int dstOf(const int* ei, int e) {
  return (e < E_RAW) ? ei[E_RAW + e] : (e - E_RAW);
}
__device__ __forceinline__ int srcOf(const int* ei, int e) {
  return (e < E_RAW) ? ei[e] : (e - E_RAW);
}
__device__ __forceinline__ float lrelu(float v) { return v > 0.f ? v : NEG_SLOPE * v; }

__device__ __forceinline__ unsigned short f2bf(float f) {
  __hip_bfloat16 h = __float2bfloat16(f);           // RN
  return reinterpret_cast<unsigned short&>(h);
}
__device__ __forceinline__ float bf2f(unsigned short u) {
  return __uint_as_float(((unsigned int)u) << 16);
}

// ---- mega prep: x split + W1/W2 transpose-split + deg zero (one dispatch) --
__global__ void mega_prep(const float* __restrict__ x,
                          unsigned short* __restrict__ xhi, unsigned short* __restrict__ xlo,
                          const float* __restrict__ W1,
                          unsigned short* __restrict__ w1hi, unsigned short* __restrict__ w1lo,
                          const float* __restrict__ W2,
                          unsigned short* __restrict__ w2hi, unsigned short* __restrict__ w2lo,
                          int* __restrict__ deg) {
  const int bid = blockIdx.x, t = threadIdx.x;
  if (bid < 10000) {                                 // x: 20000*128 = 10000 blocks exact
    int i = bid * 256 + t;
    float v = x[i];
    unsigned short hh = f2bf(v);
    xhi[i] = hh; xlo[i] = f2bf(v - bf2f(hh));
  } else if (bid < 10128) {                          // W1: 256*128 = 128 blocks
    int idx = (bid - 10000) * 256 + t;
    int c = idx >> 7, k = idx & 127;
    float v = W1[k * FC + c];
    unsigned short hh = f2bf(v);
    w1hi[c * 128 + k] = hh; w1lo[c * 128 + k] = f2bf(v - bf2f(hh));
  } else if (bid < 10384) {                          // W2: 256*256 = 256 blocks
    int idx = (bid - 10128) * 256 + t;
    int c = idx >> 8, k = idx & 255;
    float v = W2[k * FC + c];
    unsigned short hh = f2bf(v);
    w2hi[c * 256 + k] = hh; w2lo[c * 256 + k] = f2bf(v - bf2f(hh));
  } else {                                           // deg zero: 79 blocks
    int i = (bid - 10384) * 256 + t;
    if (i < N_NODESC) deg[i] = 0;
  }
}

// ---------- MFMA GEMM + fused alpha (R11 structure, 64 rows/block) ---------
template<int K>
__global__ void __launch_bounds__(256) mfma_gemm(
    const unsigned short* __restrict__ Ahi, const unsigned short* __restrict__ Alo,
    const unsigned short* __restrict__ WhiT, const unsigned short* __restrict__ WloT,
    const float* __restrict__ a_src, const float* __restrict__ a_dst,
    unsigned short* __restrict__ hb, float* __restrict__ as, float* __restrict__ ad) {
  __shared__ float asred[64][4];
  __shared__ float adred[64][4];
  const int t = threadIdx.x;
  const int w = t >> 6, l = t & 63;
  const int n0 = blockIdx.x * 64;
  const int r16 = l & 15;
  const int kq = l >> 4;
  const int col0 = w * 64;

  f32x4 acc[4][4];
#pragma unroll
  for (int rt = 0; rt < 4; ++rt)
#pragma unroll
    for (int ct = 0; ct < 4; ++ct) acc[rt][ct] = f32x4{0.f, 0.f, 0.f, 0.f};

  long arow[4];
#pragma unroll
  for (int rt = 0; rt < 4; ++rt) {
    int r = n0 + rt * 16 + r16;
    if (r >= N_NODESC) r = N_NODESC - 1;
    arow[rt] = (long)r * K;
  }

  for (int ks = 0; ks < K; ks += 32) {
    const int kb = ks + kq * 8;
    short8v aHi[4], aLo[4];
#pragma unroll
    for (int rt = 0; rt < 4; ++rt) {
      aHi[rt] = *(const short8v*)(Ahi + arow[rt] + kb);
      aLo[rt] = *(const short8v*)(Alo + arow[rt] + kb);
    }
#pragma unroll
    for (int ct = 0; ct < 4; ++ct) {
      const long wrow = (long)(col0 + ct * 16 + r16) * K + kb;
      short8v wHi = *(const short8v*)(WhiT + wrow);
      short8v wLo = *(const short8v*)(WloT + wrow);
#pragma unroll
      for (int rt = 0; rt < 4; ++rt) {
        acc[rt][ct] = __builtin_amdgcn_mfma_f32_16x16x32_bf16(aHi[rt], wHi, acc[rt][ct], 0, 0, 0);
        acc[rt][ct] = __builtin_amdgcn_mfma_f32_16x16x32_bf16(aHi[rt], wLo, acc[rt][ct], 0, 0, 0);
        acc[rt][ct] = __builtin_amdgcn_mfma_f32_16x16x32_bf16(aLo[rt], wHi, acc[rt][ct], 0, 0, 0);
      }
    }
  }

  float asv[4], adv[4];
#pragma unroll
  for (int ct = 0; ct < 4; ++ct) {
    int c = col0 + ct * 16 + r16;
    asv[ct] = a_src[c];
    adv[ct] = a_dst[c];
  }
#pragma unroll
  for (int rt = 0; rt < 4; ++rt) {
#pragma unroll
    for (int j = 0; j < 4; ++j) {
      const int r = rt * 16 + kq * 4 + j;
      const int g = n0 + r;
      if (g < N_NODESC) {
#pragma unroll
        for (int ct = 0; ct < 4; ++ct)
          hb[(long)g * FC + col0 + ct * 16 + r16] = f2bf(acc[rt][ct][j]);
      }
      float ps = acc[rt][0][j] * asv[0] + acc[rt][1][j] * asv[1]
               + acc[rt][2][j] * asv[2] + acc[rt][3][j] * asv[3];
      float pd = acc[rt][0][j] * adv[0] + acc[rt][1][j] * adv[1]
               + acc[rt][2][j] * adv[2] + acc[rt][3][j] * adv[3];
      for (int off = 8; off; off >>= 1) {
        ps += __shfl_down(ps, off, 16);
        pd += __shfl_down(pd, off, 16);
      }
      if (r16 == 0) {
        asred[r][w] = ps;
        adred[r][w] = pd;
      }
    }
  }
  __syncthreads();
  {
    const int rr = t >> 2, hh = t & 3;
    const int g = n0 + rr;
    if (g < N_NODESC) {
      as[(long)g * HEADSC + hh] = asred[rr][hh];
      ad[(long)g * HEADSC + hh] = adred[rr][hh];
    }
  }
}

// ------------- layer3 projection: h3[n] = act[n,:] . W3, + alphas ----------
__global__ void gemm3_kernel(const unsigned short* __restrict__ act_hi,
                             const unsigned short* __restrict__ act_lo,
                             const float* __restrict__ W3,
                             const float* __restrict__ asc, const float* __restrict__ adc,
                             float* __restrict__ h3, float* __restrict__ as,
                             float* __restrict__ ad) {
  const int n = blockIdx.x;
  const int t = threadIdx.x;            // 256
  float a = bf2f(act_hi[(long)n * FC + t]) + bf2f(act_lo[(long)n * FC + t]);
  float v = a * W3[t];
  for (int off = 32; off; off >>= 1) v += __shfl_down(v, off, 64);
  __shared__ float red[4];
  if ((t & 63) == 0) red[t >> 6] = v;
  __syncthreads();
  if (t == 0) {
    float s = red[0] + red[1] + red[2] + red[3];
    h3[n] = s;
    as[n] = s * asc[0];
    ad[n] = s * adc[0];
  }
}

// ----------------------------- CSR build -----------------------------------
__global__ void deg_count(const int* __restrict__ ei, int* __restrict__ deg) {
  int e = blockIdx.x * 256 + threadIdx.x;
  if (e >= E_TOTC) return;
  atomicAdd(&deg[dstOf(ei, e)], 1);
}

__global__ void scan_kernel(const int* __restrict__ deg, int* __restrict__ row_ptr,
                            int* __restrict__ cursor) {
  __shared__ int partial[1024];
  const int t = threadIdx.x;                       // 1024 threads, single block
  const int PER = (N_NODESC + 1023) / 1024;        // 20
  const int base = t * PER;
  int s = 0;
  for (int i = 0; i < PER; ++i) {
    int idx = base + i;
    if (idx < N_NODESC) s += deg[idx];
  }
  partial[t] = s;
  __syncthreads();
  for (int off = 1; off < 1024; off <<= 1) {
    int v = (t >= off) ? partial[t - off] : 0;
    __syncthreads();
    partial[t] += v;
    __syncthreads();
  }
  int run = (t == 0) ? 0 : partial[t - 1];
  for (int i = 0; i < PER; ++i) {
    int idx = base + i;
    if (idx < N_NODESC) {
      row_ptr[idx] = run;
      cursor[idx]  = run;
      run += deg[idx];
    }
  }
  if (t == 1023) row_ptr[N_NODESC] = run;          // = E_TOTC
}

__global__ void fill_kernel(const int* __restrict__ ei, int* __restrict__ cursor,
                            int* __restrict__ col_src) {
  int e = blockIdx.x * 256 + threadIdx.x;
  if (e >= E_TOTC) return;
  int d = dstOf(ei, e);
  int pos = atomicAdd(&cursor[d], 1);
  col_src[pos] = srcOf(ei, e);
}

// --- FUSED softmax+agg: 1 node/block, 128 threads ---------------------------
// Phase A (both waves): lrelu->max->exp->sum over the node's edges, weights
// cached in LDS. Phase B: unroll-8 channel gather (thread = 2 channels).
template<bool ELU>
__global__ void __launch_bounds__(128) fused_sa(
    const int* __restrict__ row_ptr, const int* __restrict__ col_src,
    const float4* __restrict__ as4, const float4* __restrict__ ad4,
    const unsigned short* __restrict__ hb, const float* __restrict__ b,
    unsigned short* __restrict__ out_hi, unsigned short* __restrict__ out_lo) {
  const int d = blockIdx.x;
  const int t = threadIdx.x;                 // 0..127
  const int l = t & 63, wv = t >> 6;
  const int j0 = row_ptr[d], j1 = row_ptr[d + 1];
  const int deg = j1 - j0;
  __shared__ float4 wbuf[MAXD];
  __shared__ float4 xred[2];
  const float4 adv = ad4[d];

  // pass 1: lrelu + running max (stash pre-exp values in LDS)
  float4 mx = float4{-INFINITY, -INFINITY, -INFINITY, -INFINITY};
  for (int j = j0 + t; j < j1; j += 128) {
    float4 a = as4[col_src[j]];
    float4 v;
    v.x = lrelu(a.x + adv.x); v.y = lrelu(a.y + adv.y);
    v.z = lrelu(a.z + adv.z); v.w = lrelu(a.w + adv.w);
    int jj = j - j0;
    if (jj < MAXD) wbuf[jj] = v;
    mx.x = fmaxf(mx.x, v.x); mx.y = fmaxf(mx.y, v.y);
    mx.z = fmaxf(mx.z, v.z); mx.w = fmaxf(mx.w, v.w);
  }
  for (int off = 32; off; off >>= 1) {
    mx.x = fmaxf(mx.x, __shfl_xor(mx.x, off, 64));
    mx.y = fmaxf(mx.y, __shfl_xor(mx.y, off, 64));
    mx.z = fmaxf(mx.z, __shfl_xor(mx.z, off, 64));
    mx.w = fmaxf(mx.w, __shfl_xor(mx.w, off, 64));
  }
  if (l == 0) xred[wv] = mx;
  __syncthreads();
  {
    float4 m0 = xred[0], m1 = xred[1];
    mx.x = fmaxf(m0.x, m1.x); mx.y = fmaxf(m0.y, m1.y);
    mx.z = fmaxf(m0.z, m1.z); mx.w = fmaxf(m0.w, m1.w);
  }
  __syncthreads();                           // protect xred before reuse

  // pass 2: exp + sum (each thread revisits only its own LDS entries)
  float4 sm = float4{0.f, 0.f, 0.f, 0.f};
  for (int j = j0 + t; j < j1; j += 128) {
    int jj = j - j0;
    float4 v;
    if (jj < MAXD) v = wbuf[jj];
    else {
      float4 a = as4[col_src[j]];
      v.x = lrelu(a.x + adv.x); v.y = lrelu(a.y + adv.y);
      v.z = lrelu(a.z + adv.z); v.w = lrelu(a.w + adv.w);
    }
    float4 e;
    e.x = expf(v.x - mx.x); e.y = expf(v.y - mx.y);
    e.z = expf(v.z - mx.z); e.w = expf(v.w - mx.w);
    if (jj < MAXD) wbuf[jj] = e;
    sm.x += e.x; sm.y += e.y; sm.z += e.z; sm.w += e.w;
  }
  for (int off = 32; off; off >>= 1) {
    sm.x += __shfl_xor(sm.x, off, 64);
    sm.y += __shfl_xor(sm.y, off, 64);
    sm.z += __shfl_xor(sm.z, off, 64);
    sm.w += __shfl_xor(sm.w, off, 64);
  }
  if (l == 0) xred[wv] = sm;
  __syncthreads();                           // also publishes wbuf exps to all

  const int h = t >> 5;                      // head of channel pair (2t, 2t+1)
  float st0, mxh, advh;
  {
    float4 s0 = xred[0], s1 = xred[1];
    float sx = s0.x + s1.x, sy = s0.y + s1.y, sz = s0.z + s1.z, sw = s0.w + s1.w;
    st0  = (h == 0) ? sx : (h == 1) ? sy : (h == 2) ? sz : sw;
    mxh  = (h == 0) ? mx.x : (h == 1) ? mx.y : (h == 2) ? mx.z : mx.w;
    advh = (h == 0) ? adv.x : (h == 1) ? adv.y : (h == 2) ? adv.z : adv.w;
  }
  const float dnh = 1.f / st0;

  // phase B: channel gather
  const float* wlds = (const float*)wbuf;
  const ushort2* hb2 = (const ushort2*)hb;
  float a0 = 0.f, a1 = 0.f;
  if (deg <= MAXD) {
    int j = j0;
    for (; j + 8 <= j1; j += 8) {
      int     s[8];
      ushort2 v[8];
      float   w[8];
#pragma unroll
      for (int u = 0; u < 8; ++u) s[u] = col_src[j + u];
#pragma unroll
      for (int u = 0; u < 8; ++u) v[u] = hb2[(long)s[u] * 128 + t];
#pragma unroll
      for (int u = 0; u < 8; ++u) w[u] = wlds[(j + u - j0) * 4 + h];
#pragma unroll
      for (int u = 0; u < 8; ++u) {
        a0 = fmaf(w[u], bf2f(v[u].x), a0);
        a1 = fmaf(w[u], bf2f(v[u].y), a1);
      }
    }
    for (; j < j1; ++j) {
      ushort2 v = hb2[(long)col_src[j] * 128 + t];
      float w = wlds[(j - j0) * 4 + h];
      a0 = fmaf(w, bf2f(v.x), a0);
      a1 = fmaf(w, bf2f(v.y), a1);
    }
  } else {                                   // ultra-rare: recompute weights
    const float* asf = (const float*)as4;
    for (int j = j0; j < j1; ++j) {
      int s = col_src[j];
      float e = expf(lrelu(asf[s * 4 + h] + advh) - mxh);
      ushort2 v = hb2[(long)s * 128 + t];
      a0 = fmaf(e, bf2f(v.x), a0);
      a1 = fmaf(e, bf2f(v.y), a1);
    }
  }
  float o0 = a0 * dnh + b[2 * t];
  float o1 = a1 * dnh + b[2 * t + 1];
  if (ELU) {
    o0 = o0 > 0.f ? o0 : expm1f(o0);
    o1 = o1 > 0.f ? o1 : expm1f(o1);
  }
  ushort2 hi, lo;
  hi.x = f2bf(o0); lo.x = f2bf(o0 - bf2f(hi.x));
  hi.y = f2bf(o1); lo.y = f2bf(o1 - bf2f(hi.y));
  ((ushort2*)out_hi)[(long)d * 128 + t] = hi;
  ((ushort2*)out_lo)[(long)d * 128 + t] = lo;
}

// --- FUSED layer3 softmax+agg: out = sum(e*h3)/sum(e), wave per node -------
__global__ void __launch_bounds__(256) fused_sa3(
    const int* __restrict__ row_ptr, const int* __restrict__ col_src,
    const float* __restrict__ as, const float* __restrict__ ad,
    const float* __restrict__ h3, const float* __restrict__ b3,
    float* __restrict__ out) {
  const int wv = threadIdx.x >> 6, l = threadIdx.x & 63;
  const int d = blockIdx.x * 4 + wv;
  if (d >= N_NODESC) return;
  const int j0 = row_ptr[d], j1 = row_ptr[d + 1];
  const float adv = ad[d];
  float mx = -INFINITY;
  for (int j = j0 + l; j < j1; j += 64)
    mx = fmaxf(mx, lrelu(as[col_src[j]] + adv));
  for (int off = 32; off; off >>= 1) mx = fmaxf(mx, __shfl_xor(mx, off, 64));
  float sm = 0.f, acc = 0.f;
  for (int j = j0 + l; j < j1; j += 64) {
    int s = col_src[j];
    float e = expf(lrelu(as[s] + adv) - mx);
    sm += e;
    acc = fmaf(e, h3[s], acc);
  }
  for (int off = 32; off; off >>= 1) {
    sm  += __shfl_xor(sm, off, 64);
    acc += __shfl_xor(acc, off, 64);
  }
  if (l == 0) out[d] = acc / sm + b3[0];
}

extern "C" void kernel_launch(void* const* d_in, const int* in_sizes, int n_in,
                              void* d_out, int out_size, void* d_ws, size_t ws_size,
                              hipStream_t stream) {
  const float* x    = (const float*)d_in[0];
  const int*   ei   = (const int*)d_in[1];
  const float* W1   = (const float*)d_in[2];
  const float* as1  = (const float*)d_in[3];
  const float* ad1  = (const float*)d_in[4];
  const float* b1   = (const float*)d_in[5];
  const float* W2   = (const float*)d_in[6];
  const float* as2  = (const float*)d_in[7];
  const float* ad2  = (const float*)d_in[8];
  const float* b2   = (const float*)d_in[9];
  const float* W3   = (const float*)d_in[10];
  const float* as3  = (const float*)d_in[11];
  const float* ad3  = (const float*)d_in[12];
  const float* b3   = (const float*)d_in[13];
  float* out = (float*)d_out;

  float* ws = (float*)d_ws;
  size_t off = 0;
  float* wAs   = ws + off; off += (size_t)N_NODESC * HEADSC;
  float* wAd   = ws + off; off += (size_t)N_NODESC * HEADSC;
  float* h3    = ws + off; off += N_NODESC;
  int* deg     = (int*)(ws + off); off += N_NODESC;
  int* row_ptr = (int*)(ws + off); off += N_NODESC + 1;
  int* cursor  = (int*)(ws + off); off += N_NODESC;
  int* col_src = (int*)(ws + off); off += E_TOTC;
  off = (off + 3) & ~(size_t)3;                     // 16B align for bf16 vectors
  unsigned short* hb     = (unsigned short*)(ws + off); off += (size_t)N_NODESC * 128;
  unsigned short* act_hi = (unsigned short*)(ws + off); off += (size_t)N_NODESC * 128;
  unsigned short* act_lo = (unsigned short*)(ws + off); off += (size_t)N_NODESC * 128;
  unsigned short* xhi    = (unsigned short*)(ws + off); off += (size_t)N_NODESC * 64;
  unsigned short* xlo    = (unsigned short*)(ws + off); off += (size_t)N_NODESC * 64;
  unsigned short* W1hiT  = (unsigned short*)(ws + off); off += 16384;   // 32768 ush
  unsigned short* W1loT  = (unsigned short*)(ws + off); off += 16384;
  unsigned short* W2hiT  = (unsigned short*)(ws + off); off += 32768;   // 65536 ush
  unsigned short* W2loT  = (unsigned short*)(ws + off); off += 32768;

  const int gridE  = (E_TOTC + 255) / 256;
  const int gridN4 = (N_NODESC + 3) / 4;
  const int gemmG  = (N_NODESC + 63) / 64;          // 313

  // ---------------- prep (1 dispatch) + CSR build --------------------------
  mega_prep<<<10463, 256, 0, stream>>>(x, xhi, xlo, W1, W1hiT, W1loT,
                                       W2, W2hiT, W2loT, deg);
  deg_count<<<gridE, 256, 0, stream>>>(ei, deg);
  scan_kernel<<<1, 1024, 0, stream>>>(deg, row_ptr, cursor);
  fill_kernel<<<gridE, 256, 0, stream>>>(ei, cursor, col_src);

  // ---------------- layer 1 (K=128) ----------------
  mfma_gemm<128><<<gemmG, 256, 0, stream>>>(xhi, xlo, W1hiT, W1loT, as1, ad1, hb, wAs, wAd);
  fused_sa<true><<<N_NODESC, 128, 0, stream>>>(row_ptr, col_src, (const float4*)wAs,
                                               (const float4*)wAd, hb, b1, act_hi, act_lo);

  // ---------------- layer 2 (K=256) ----------------
  mfma_gemm<256><<<gemmG, 256, 0, stream>>>(act_hi, act_lo, W2hiT, W2loT, as2, ad2, hb, wAs, wAd);
  fused_sa<true><<<N_NODESC, 128, 0, stream>>>(row_ptr, col_src, (const float4*)wAs,
                                               (const float4*)wAd, hb, b2, act_hi, act_lo);

  // ---------------- layer 3 (heads=1, out=1) ----------------
  gemm3_kernel<<<N_NODESC, 256, 0, stream>>>(act_hi, act_lo, W3, as3, ad3, h3, wAs, wAd);
  fused_sa3<<<gridN4, 256, 0, stream>>>(row_ptr, col_src, wAs, wAd, h3, b3, out);
}

// Round 13
// 233.144 us; speedup vs baseline: 1.2762x; 1.0043x over previous
//
#include <hip/hip_runtime.h>
#include <hip/hip_bf16.h>
#include <cmath>

#define N_NODESC 20000
#define E_RAW    320000
#define E_TOTC   340000   // + self loops
#define HEADSC   4
#define FC       256      // HEADS*HID
#define NEG_SLOPE 0.2f
#define MAXD     512      // per-node edge cap held in LDS (true max deg ~50)

typedef __attribute__((ext_vector_type(8))) short short8v;   // 8 bf16 = 4 VGPR
typedef __attribute__((ext_vector_type(4))) float f32x4;

__device__ __forceinline__ int dstOf(const int* ei, int e) {
  return (e < E_RAW) ? ei[E_RAW + e] : (e - E_RAW);
}
__device__ __forceinline__ int srcOf(const int* ei, int e) {
  return (e < E_RAW) ? ei[e] : (e - E_RAW);
}
__device__ __forceinline__ float lrelu(float v) { return v > 0.f ? v : NEG_SLOPE * v; }

__device__ __forceinline__ unsigned short f2bf(float f) {
  __hip_bfloat16 h = __float2bfloat16(f);           // RN
  return reinterpret_cast<unsigned short&>(h);
}
__device__ __forceinline__ float bf2f(unsigned short u) {
  return __uint_as_float(((unsigned int)u) << 16);
}

// ---- mega prep: x split + W1/W2 transpose-split + deg zero (one dispatch) --
__global__ void mega_prep(const float* __restrict__ x,
                          unsigned short* __restrict__ xhi, unsigned short* __restrict__ xlo,
                          const float* __restrict__ W1,
                          unsigned short* __restrict__ w1hi, unsigned short* __restrict__ w1lo,
                          const float* __restrict__ W2,
                          unsigned short* __restrict__ w2hi, unsigned short* __restrict__ w2lo,
                          int* __restrict__ deg) {
  const int bid = blockIdx.x, t = threadIdx.x;
  if (bid < 10000) {                                 // x: 20000*128 = 10000 blocks exact
    int i = bid * 256 + t;
    float v = x[i];
    unsigned short hh = f2bf(v);
    xhi[i] = hh; xlo[i] = f2bf(v - bf2f(hh));
  } else if (bid < 10128) {                          // W1: 256*128 = 128 blocks
    int idx = (bid - 10000) * 256 + t;
    int c = idx >> 7, k = idx & 127;
    float v = W1[k * FC + c];
    unsigned short hh = f2bf(v);
    w1hi[c * 128 + k] = hh; w1lo[c * 128 + k] = f2bf(v - bf2f(hh));
  } else if (bid < 10384) {                          // W2: 256*256 = 256 blocks
    int idx = (bid - 10128) * 256 + t;
    int c = idx >> 8, k = idx & 255;
    float v = W2[k * FC + c];
    unsigned short hh = f2bf(v);
    w2hi[c * 256 + k] = hh; w2lo[c * 256 + k] = f2bf(v - bf2f(hh));
  } else {                                           // deg zero: 79 blocks
    int i = (bid - 10384) * 256 + t;
    if (i < N_NODESC) deg[i] = 0;
  }
}

// ---------- MFMA GEMM + fused alpha (64 rows/block) ------------------------
template<int K>
__global__ void __launch_bounds__(256) mfma_gemm(
    const unsigned short* __restrict__ Ahi, const unsigned short* __restrict__ Alo,
    const unsigned short* __restrict__ WhiT, const unsigned short* __restrict__ WloT,
    const float* __restrict__ a_src, const float* __restrict__ a_dst,
    unsigned short* __restrict__ hb, float* __restrict__ as, float* __restrict__ ad) {
  __shared__ float asred[64][4];
  __shared__ float adred[64][4];
  const int t = threadIdx.x;
  const int w = t >> 6, l = t & 63;
  const int n0 = blockIdx.x * 64;
  const int r16 = l & 15;
  const int kq = l >> 4;
  const int col0 = w * 64;

  f32x4 acc[4][4];
#pragma unroll
  for (int rt = 0; rt < 4; ++rt)
#pragma unroll
    for (int ct = 0; ct < 4; ++ct) acc[rt][ct] = f32x4{0.f, 0.f, 0.f, 0.f};

  long arow[4];
#pragma unroll
  for (int rt = 0; rt < 4; ++rt) {
    int r = n0 + rt * 16 + r16;
    if (r >= N_NODESC) r = N_NODESC - 1;
    arow[rt] = (long)r * K;
  }

  for (int ks = 0; ks < K; ks += 32) {
    const int kb = ks + kq * 8;
    short8v aHi[4], aLo[4];
#pragma unroll
    for (int rt = 0; rt < 4; ++rt) {
      aHi[rt] = *(const short8v*)(Ahi + arow[rt] + kb);
      aLo[rt] = *(const short8v*)(Alo + arow[rt] + kb);
    }
#pragma unroll
    for (int ct = 0; ct < 4; ++ct) {
      const long wrow = (long)(col0 + ct * 16 + r16) * K + kb;
      short8v wHi = *(const short8v*)(WhiT + wrow);
      short8v wLo = *(const short8v*)(WloT + wrow);
#pragma unroll
      for (int rt = 0; rt < 4; ++rt) {
        acc[rt][ct] = __builtin_amdgcn_mfma_f32_16x16x32_bf16(aHi[rt], wHi, acc[rt][ct], 0, 0, 0);
        acc[rt][ct] = __builtin_amdgcn_mfma_f32_16x16x32_bf16(aHi[rt], wLo, acc[rt][ct], 0, 0, 0);
        acc[rt][ct] = __builtin_amdgcn_mfma_f32_16x16x32_bf16(aLo[rt], wHi, acc[rt][ct], 0, 0, 0);
      }
    }
  }

  float asv[4], adv[4];
#pragma unroll
  for (int ct = 0; ct < 4; ++ct) {
    int c = col0 + ct * 16 + r16;
    asv[ct] = a_src[c];
    adv[ct] = a_dst[c];
  }
#pragma unroll
  for (int rt = 0; rt < 4; ++rt) {
#pragma unroll
    for (int j = 0; j < 4; ++j) {
      const int r = rt * 16 + kq * 4 + j;
      const int g = n0 + r;
      if (g < N_NODESC) {
#pragma unroll
        for (int ct = 0; ct < 4; ++ct)
          hb[(long)g * FC + col0 + ct * 16 + r16] = f2bf(acc[rt][ct][j]);
      }
      float ps = acc[rt][0][j] * asv[0] + acc[rt][1][j] * asv[1]
               + acc[rt][2][j] * asv[2] + acc[rt][3][j] * asv[3];
      float pd = acc[rt][0][j] * adv[0] + acc[rt][1][j] * adv[1]
               + acc[rt][2][j] * adv[2] + acc[rt][3][j] * adv[3];
      for (int off = 8; off; off >>= 1) {
        ps += __shfl_down(ps, off, 16);
        pd += __shfl_down(pd, off, 16);
      }
      if (r16 == 0) {
        asred[r][w] = ps;
        adred[r][w] = pd;
      }
    }
  }
  __syncthreads();
  {
    const int rr = t >> 2, hh = t & 3;
    const int g = n0 + rr;
    if (g < N_NODESC) {
      as[(long)g * HEADSC + hh] = asred[rr][hh];
      ad[(long)g * HEADSC + hh] = adred[rr][hh];
    }
  }
}

// ----------------------------- CSR build -----------------------------------
__global__ void deg_count(const int* __restrict__ ei, int* __restrict__ deg) {
  int e = blockIdx.x * 256 + threadIdx.x;
  if (e >= E_TOTC) return;
  atomicAdd(&deg[dstOf(ei, e)], 1);
}

// 1024-thread single-block scan, 2 barriers (wave shfl_up + 16-entry LDS pass)
__global__ void scan_kernel(const int* __restrict__ deg, int* __restrict__ row_ptr,
                            int* __restrict__ cursor) {
  const int t = threadIdx.x;
  const int lane = t & 63, wid = t >> 6;           // 16 waves
  const int PER = (N_NODESC + 1023) / 1024;        // 20
  const int base = t * PER;
  int own = 0;
  for (int i = 0; i < PER; ++i) {
    int idx = base + i;
    if (idx < N_NODESC) own += deg[idx];
  }
  int inc = own;
  for (int off = 1; off < 64; off <<= 1) {
    int v = __shfl_up(inc, off, 64);
    if (lane >= off) inc += v;
  }
  __shared__ int wtot[16], woff[16];
  if (lane == 63) wtot[wid] = inc;
  __syncthreads();
  if (t == 0) {
    int r = 0;
    for (int i = 0; i < 16; ++i) { woff[i] = r; r += wtot[i]; }
  }
  __syncthreads();
  int run = woff[wid] + inc - own;
  for (int i = 0; i < PER; ++i) {
    int idx = base + i;
    if (idx < N_NODESC) {
      row_ptr[idx] = run;
      cursor[idx]  = run;
      run += deg[idx];
    }
  }
  if (t == 1023) row_ptr[N_NODESC] = run;          // = E_TOTC
}

__global__ void fill_kernel(const int* __restrict__ ei, int* __restrict__ cursor,
                            int* __restrict__ col_src) {
  int e = blockIdx.x * 256 + threadIdx.x;
  if (e >= E_TOTC) return;
  int d = dstOf(ei, e);
  int pos = atomicAdd(&cursor[d], 1);
  col_src[pos] = srcOf(ei, e);
}

// --- FUSED softmax+agg: 1 node/block, 128 threads ---------------------------
// MODE 0: write ELU'd act as bf16 hi/lo (layer 1).
// MODE 1: additionally fold in gemm3: h3[d] = act_row . W3, alphas — no act store.
template<int MODE>
__global__ void __launch_bounds__(128) fused_sa(
    const int* __restrict__ row_ptr, const int* __restrict__ col_src,
    const float4* __restrict__ as4, const float4* __restrict__ ad4,
    const unsigned short* __restrict__ hb, const float* __restrict__ b,
    unsigned short* __restrict__ out_hi, unsigned short* __restrict__ out_lo,
    const float* __restrict__ W3, const float* __restrict__ asc3,
    const float* __restrict__ adc3, float* __restrict__ h3,
    float* __restrict__ a3s, float* __restrict__ a3d) {
  const int d = blockIdx.x;
  const int t = threadIdx.x;                 // 0..127
  const int l = t & 63, wv = t >> 6;
  const int j0 = row_ptr[d], j1 = row_ptr[d + 1];
  const int deg = j1 - j0;
  __shared__ float4 wbuf[MAXD];
  __shared__ float4 xred[2];
  const float4 adv = ad4[d];

  // pass 1: lrelu + running max (stash pre-exp values in LDS)
  float4 mx = float4{-INFINITY, -INFINITY, -INFINITY, -INFINITY};
  for (int j = j0 + t; j < j1; j += 128) {
    float4 a = as4[col_src[j]];
    float4 v;
    v.x = lrelu(a.x + adv.x); v.y = lrelu(a.y + adv.y);
    v.z = lrelu(a.z + adv.z); v.w = lrelu(a.w + adv.w);
    int jj = j - j0;
    if (jj < MAXD) wbuf[jj] = v;
    mx.x = fmaxf(mx.x, v.x); mx.y = fmaxf(mx.y, v.y);
    mx.z = fmaxf(mx.z, v.z); mx.w = fmaxf(mx.w, v.w);
  }
  for (int off = 32; off; off >>= 1) {
    mx.x = fmaxf(mx.x, __shfl_xor(mx.x, off, 64));
    mx.y = fmaxf(mx.y, __shfl_xor(mx.y, off, 64));
    mx.z = fmaxf(mx.z, __shfl_xor(mx.z, off, 64));
    mx.w = fmaxf(mx.w, __shfl_xor(mx.w, off, 64));
  }
  if (l == 0) xred[wv] = mx;
  __syncthreads();
  {
    float4 m0 = xred[0], m1 = xred[1];
    mx.x = fmaxf(m0.x, m1.x); mx.y = fmaxf(m0.y, m1.y);
    mx.z = fmaxf(m0.z, m1.z); mx.w = fmaxf(m0.w, m1.w);
  }
  __syncthreads();                           // protect xred before reuse

  // pass 2: exp + sum
  float4 sm = float4{0.f, 0.f, 0.f, 0.f};
  for (int j = j0 + t; j < j1; j += 128) {
    int jj = j - j0;
    float4 v;
    if (jj < MAXD) v = wbuf[jj];
    else {
      float4 a = as4[col_src[j]];
      v.x = lrelu(a.x + adv.x); v.y = lrelu(a.y + adv.y);
      v.z = lrelu(a.z + adv.z); v.w = lrelu(a.w + adv.w);
    }
    float4 e;
    e.x = expf(v.x - mx.x); e.y = expf(v.y - mx.y);
    e.z = expf(v.z - mx.z); e.w = expf(v.w - mx.w);
    if (jj < MAXD) wbuf[jj] = e;
    sm.x += e.x; sm.y += e.y; sm.z += e.z; sm.w += e.w;
  }
  for (int off = 32; off; off >>= 1) {
    sm.x += __shfl_xor(sm.x, off, 64);
    sm.y += __shfl_xor(sm.y, off, 64);
    sm.z += __shfl_xor(sm.z, off, 64);
    sm.w += __shfl_xor(sm.w, off, 64);
  }
  if (l == 0) xred[wv] = sm;
  __syncthreads();                           // also publishes wbuf exps

  const int h = t >> 5;                      // head of channel pair (2t, 2t+1)
  float st0, mxh, advh;
  {
    float4 s0 = xred[0], s1 = xred[1];
    float sx = s0.x + s1.x, sy = s0.y + s1.y, sz = s0.z + s1.z, sw = s0.w + s1.w;
    st0  = (h == 0) ? sx : (h == 1) ? sy : (h == 2) ? sz : sw;
    mxh  = (h == 0) ? mx.x : (h == 1) ? mx.y : (h == 2) ? mx.z : mx.w;
    advh = (h == 0) ? adv.x : (h == 1) ? adv.y : (h == 2) ? adv.z : adv.w;
  }
  const float dnh = 1.f / st0;

  // phase B: channel gather
  const float* wlds = (const float*)wbuf;
  const ushort2* hb2 = (const ushort2*)hb;
  float a0 = 0.f, a1 = 0.f;
  if (deg <= MAXD) {
    int j = j0;
    for (; j + 8 <= j1; j += 8) {
      int     s[8];
      ushort2 v[8];
      float   w[8];
#pragma unroll
      for (int u = 0; u < 8; ++u) s[u] = col_src[j + u];
#pragma unroll
      for (int u = 0; u < 8; ++u) v[u] = hb2[(long)s[u] * 128 + t];
#pragma unroll
      for (int u = 0; u < 8; ++u) w[u] = wlds[(j + u - j0) * 4 + h];
#pragma unroll
      for (int u = 0; u < 8; ++u) {
        a0 = fmaf(w[u], bf2f(v[u].x), a0);
        a1 = fmaf(w[u], bf2f(v[u].y), a1);
      }
    }
    for (; j < j1; ++j) {
      ushort2 v = hb2[(long)col_src[j] * 128 + t];
      float w = wlds[(j - j0) * 4 + h];
      a0 = fmaf(w, bf2f(v.x), a0);
      a1 = fmaf(w, bf2f(v.y), a1);
    }
  } else {                                   // ultra-rare: recompute weights
    const float* asf = (const float*)as4;
    for (int j = j0; j < j1; ++j) {
      int s = col_src[j];
      float e = expf(lrelu(asf[s * 4 + h] + advh) - mxh);
      ushort2 v = hb2[(long)s * 128 + t];
      a0 = fmaf(e, bf2f(v.x), a0);
      a1 = fmaf(e, bf2f(v.y), a1);
    }
  }
  float o0 = a0 * dnh + b[2 * t];
  float o1 = a1 * dnh + b[2 * t + 1];
  o0 = o0 > 0.f ? o0 : expm1f(o0);           // ELU (both layers feeding next)
  o1 = o1 > 0.f ? o1 : expm1f(o1);

  if (MODE == 0) {
    ushort2 hi, lo;
    hi.x = f2bf(o0); lo.x = f2bf(o0 - bf2f(hi.x));
    hi.y = f2bf(o1); lo.y = f2bf(o1 - bf2f(hi.y));
    ((ushort2*)out_hi)[(long)d * 128 + t] = hi;
    ((ushort2*)out_lo)[(long)d * 128 + t] = lo;
  } else {
    // fused gemm3: p = o . W3 chunk; block-reduce -> h3, alphas
    float p = o0 * W3[2 * t] + o1 * W3[2 * t + 1];
    for (int off = 32; off; off >>= 1) p += __shfl_down(p, off, 64);
    __shared__ float pred[2];
    if (l == 0) pred[wv] = p;
    __syncthreads();
    if (t == 0) {
      float s = pred[0] + pred[1];
      h3[d]  = s;
      a3s[d] = s * asc3[0];
      a3d[d] = s * adc3[0];
    }
  }
}

// --- FUSED layer3 softmax+agg: out = sum(e*h3)/sum(e), wave per node -------
__global__ void __launch_bounds__(256) fused_sa3(
    const int* __restrict__ row_ptr, const int* __restrict__ col_src,
    const float* __restrict__ as, const float* __restrict__ ad,
    const float* __restrict__ h3, const float* __restrict__ b3,
    float* __restrict__ out) {
  const int wv = threadIdx.x >> 6, l = threadIdx.x & 63;
  const int d = blockIdx.x * 4 + wv;
  if (d >= N_NODESC) return;
  const int j0 = row_ptr[d], j1 = row_ptr[d + 1];
  const float adv = ad[d];
  float mx = -INFINITY;
  for (int j = j0 + l; j < j1; j += 64)
    mx = fmaxf(mx, lrelu(as[col_src[j]] + adv));
  for (int off = 32; off; off >>= 1) mx = fmaxf(mx, __shfl_xor(mx, off, 64));
  float sm = 0.f, acc = 0.f;
  for (int j = j0 + l; j < j1; j += 64) {
    int s = col_src[j];
    float e = expf(lrelu(as[s] + adv) - mx);
    sm += e;
    acc = fmaf(e, h3[s], acc);
  }
  for (int off = 32; off; off >>= 1) {
    sm  += __shfl_xor(sm, off, 64);
    acc += __shfl_xor(acc, off, 64);
  }
  if (l == 0) out[d] = acc / sm + b3[0];
}

extern "C" void kernel_launch(void* const* d_in, const int* in_sizes, int n_in,
                              void* d_out, int out_size, void* d_ws, size_t ws_size,
                              hipStream_t stream) {
  const float* x    = (const float*)d_in[0];
  const int*   ei   = (const int*)d_in[1];
  const float* W1   = (const float*)d_in[2];
  const float* as1  = (const float*)d_in[3];
  const float* ad1  = (const float*)d_in[4];
  const float* b1   = (const float*)d_in[5];
  const float* W2   = (const float*)d_in[6];
  const float* as2  = (const float*)d_in[7];
  const float* ad2  = (const float*)d_in[8];
  const float* b2   = (const float*)d_in[9];
  const float* W3   = (const float*)d_in[10];
  const float* as3  = (const float*)d_in[11];
  const float* ad3  = (const float*)d_in[12];
  const float* b3   = (const float*)d_in[13];
  float* out = (float*)d_out;

  float* ws = (float*)d_ws;
  size_t off = 0;
  float* wAs   = ws + off; off += (size_t)N_NODESC * HEADSC;
  float* wAd   = ws + off; off += (size_t)N_NODESC * HEADSC;
  float* h3    = ws + off; off += N_NODESC;
  float* a3s   = ws + off; off += N_NODESC;
  float* a3d   = ws + off; off += N_NODESC;
  int* deg     = (int*)(ws + off); off += N_NODESC;
  int* row_ptr = (int*)(ws + off); off += N_NODESC + 1;
  int* cursor  = (int*)(ws + off); off += N_NODESC;
  int* col_src = (int*)(ws + off); off += E_TOTC;
  off = (off + 3) & ~(size_t)3;                     // 16B align for bf16 vectors
  unsigned short* hb     = (unsigned short*)(ws + off); off += (size_t)N_NODESC * 128;
  unsigned short* act_hi = (unsigned short*)(ws + off); off += (size_t)N_NODESC * 128;
  unsigned short* act_lo = (unsigned short*)(ws + off); off += (size_t)N_NODESC * 128;
  unsigned short* xhi    = (unsigned short*)(ws + off); off += (size_t)N_NODESC * 64;
  unsigned short* xlo    = (unsigned short*)(ws + off); off += (size_t)N_NODESC * 64;
  unsigned short* W1hiT  = (unsigned short*)(ws + off); off += 16384;   // 32768 ush
  unsigned short* W1loT  = (unsigned short*)(ws + off); off += 16384;
  unsigned short* W2hiT  = (unsigned short*)(ws + off); off += 32768;   // 65536 ush
  unsigned short* W2loT  = (unsigned short*)(ws + off); off += 32768;

  const int gridE  = (E_TOTC + 255) / 256;
  const int gridN4 = (N_NODESC + 3) / 4;
  const int gemmG  = (N_NODESC + 63) / 64;          // 313

  // ---------------- prep (1 dispatch) + CSR build --------------------------
  mega_prep<<<10463, 256, 0, stream>>>(x, xhi, xlo, W1, W1hiT, W1loT,
                                       W2, W2hiT, W2loT, deg);
  deg_count<<<gridE, 256, 0, stream>>>(ei, deg);
  scan_kernel<<<1, 1024, 0, stream>>>(deg, row_ptr, cursor);
  fill_kernel<<<gridE, 256, 0, stream>>>(ei, cursor, col_src);

  // ---------------- layer 1 (K=128) ----------------
  mfma_gemm<128><<<gemmG, 256, 0, stream>>>(xhi, xlo, W1hiT, W1loT, as1, ad1, hb, wAs, wAd);
  fused_sa<0><<<N_NODESC, 128, 0, stream>>>(row_ptr, col_src, (const float4*)wAs,
                                            (const float4*)wAd, hb, b1, act_hi, act_lo,
                                            nullptr, nullptr, nullptr, nullptr, nullptr, nullptr);

  // ---------------- layer 2 (K=256), gemm3 fused into epilogue -------------
  mfma_gemm<256><<<gemmG, 256, 0, stream>>>(act_hi, act_lo, W2hiT, W2loT, as2, ad2, hb, wAs, wAd);
  fused_sa<1><<<N_NODESC, 128, 0, stream>>>(row_ptr, col_src, (const float4*)wAs,
                                            (const float4*)wAd, hb, b2, nullptr, nullptr,
                                            W3, as3, ad3, h3, a3s, a3d);

  // ---------------- layer 3 (heads=1, out=1) ----------------
  fused_sa3<<<gridN4, 256, 0, stream>>>(row_ptr, col_src, a3s, a3d, h3, b3, out);
}

// Round 14
// 230.904 us; speedup vs baseline: 1.2886x; 1.0097x over previous
//
#include <hip/hip_runtime.h>
#include <hip/hip_bf16.h>
#include <cmath>

#define N_NODESC 20000
#define E_RAW    320000
#define E_TOTC   340000   // + self loops
#define HEADSC   4
#define FC       256      // HEADS*HID
#define NEG_SLOPE 0.2f

typedef __attribute__((ext_vector_type(8))) short short8v;   // 8 bf16 = 4 VGPR
typedef __attribute__((ext_vector_type(4))) float f32x4;

__device__ __forceinline__ int dstOf(const int* ei, int e) {
  return (e < E_RAW) ? ei[E_RAW + e] : (e - E_RAW);
}
__device__ __forceinline__ int srcOf(const int* ei, int e) {
  return (e < E_RAW) ? ei[e] : (e - E_RAW);
}
__device__ __forceinline__ float lrelu(float v) { return v > 0.f ? v : NEG_SLOPE * v; }

__device__ __forceinline__ unsigned short f2bf(float f) {
  __hip_bfloat16 h = __float2bfloat16(f);           // RN
  return reinterpret_cast<unsigned short&>(h);
}
__device__ __forceinline__ float bf2f(unsigned short u) {
  return __uint_as_float(((unsigned int)u) << 16);
}

// Order-invariant float atomic max via int/uint monotone encoding.
__device__ __forceinline__ void atomicMaxF(float* addr, float val) {
  if (val >= 0.f) atomicMax((int*)addr, __float_as_int(val));
  else            atomicMin((unsigned int*)addr, (unsigned int)__float_as_int(val));
}

// ---- mega prep: x split + W1/W2 transpose-split + deg zero + amax init ----
__global__ void mega_prep(const float* __restrict__ x,
                          unsigned short* __restrict__ xhi, unsigned short* __restrict__ xlo,
                          const float* __restrict__ W1,
                          unsigned short* __restrict__ w1hi, unsigned short* __restrict__ w1lo,
                          const float* __restrict__ W2,
                          unsigned short* __restrict__ w2hi, unsigned short* __restrict__ w2lo,
                          int* __restrict__ deg, float* __restrict__ amax) {
  const int bid = blockIdx.x, t = threadIdx.x;
  if (bid < 10000) {                                 // x: 20000*128 = 10000 blocks exact
    int i = bid * 256 + t;
    float v = x[i];
    unsigned short hh = f2bf(v);
    xhi[i] = hh; xlo[i] = f2bf(v - bf2f(hh));
  } else if (bid < 10128) {                          // W1: 256*128 = 128 blocks
    int idx = (bid - 10000) * 256 + t;
    int c = idx >> 7, k = idx & 127;
    float v = W1[k * FC + c];
    unsigned short hh = f2bf(v);
    w1hi[c * 128 + k] = hh; w1lo[c * 128 + k] = f2bf(v - bf2f(hh));
  } else if (bid < 10384) {                          // W2: 256*256 = 256 blocks
    int idx = (bid - 10128) * 256 + t;
    int c = idx >> 8, k = idx & 255;
    float v = W2[k * FC + c];
    unsigned short hh = f2bf(v);
    w2hi[c * 256 + k] = hh; w2lo[c * 256 + k] = f2bf(v - bf2f(hh));
  } else {                                           // deg zero + amax init: 79 blocks
    int i = (bid - 10384) * 256 + t;
    if (i < N_NODESC) deg[i] = 0;
    else if (i < N_NODESC + 8) amax[i - N_NODESC] = -INFINITY;
  }
}

// ---------- MFMA GEMM + fused alpha + global-as-max (64 rows/block) --------
template<int K>
__global__ void __launch_bounds__(256) mfma_gemm(
    const unsigned short* __restrict__ Ahi, const unsigned short* __restrict__ Alo,
    const unsigned short* __restrict__ WhiT, const unsigned short* __restrict__ WloT,
    const float* __restrict__ a_src, const float* __restrict__ a_dst,
    unsigned short* __restrict__ hb, float* __restrict__ as, float* __restrict__ ad,
    float* __restrict__ asmax) {
  __shared__ float asred[64][4];
  __shared__ float adred[64][4];
  __shared__ float wmax[4][4];
  const int t = threadIdx.x;
  const int w = t >> 6, l = t & 63;
  const int n0 = blockIdx.x * 64;
  const int r16 = l & 15;
  const int kq = l >> 4;
  const int col0 = w * 64;

  f32x4 acc[4][4];
#pragma unroll
  for (int rt = 0; rt < 4; ++rt)
#pragma unroll
    for (int ct = 0; ct < 4; ++ct) acc[rt][ct] = f32x4{0.f, 0.f, 0.f, 0.f};

  long arow[4];
#pragma unroll
  for (int rt = 0; rt < 4; ++rt) {
    int r = n0 + rt * 16 + r16;
    if (r >= N_NODESC) r = N_NODESC - 1;
    arow[rt] = (long)r * K;
  }

  for (int ks = 0; ks < K; ks += 32) {
    const int kb = ks + kq * 8;
    short8v aHi[4], aLo[4];
#pragma unroll
    for (int rt = 0; rt < 4; ++rt) {
      aHi[rt] = *(const short8v*)(Ahi + arow[rt] + kb);
      aLo[rt] = *(const short8v*)(Alo + arow[rt] + kb);
    }
#pragma unroll
    for (int ct = 0; ct < 4; ++ct) {
      const long wrow = (long)(col0 + ct * 16 + r16) * K + kb;
      short8v wHi = *(const short8v*)(WhiT + wrow);
      short8v wLo = *(const short8v*)(WloT + wrow);
#pragma unroll
      for (int rt = 0; rt < 4; ++rt) {
        acc[rt][ct] = __builtin_amdgcn_mfma_f32_16x16x32_bf16(aHi[rt], wHi, acc[rt][ct], 0, 0, 0);
        acc[rt][ct] = __builtin_amdgcn_mfma_f32_16x16x32_bf16(aHi[rt], wLo, acc[rt][ct], 0, 0, 0);
        acc[rt][ct] = __builtin_amdgcn_mfma_f32_16x16x32_bf16(aLo[rt], wHi, acc[rt][ct], 0, 0, 0);
      }
    }
  }

  float asv[4], adv[4];
#pragma unroll
  for (int ct = 0; ct < 4; ++ct) {
    int c = col0 + ct * 16 + r16;
    asv[ct] = a_src[c];
    adv[ct] = a_dst[c];
  }
#pragma unroll
  for (int rt = 0; rt < 4; ++rt) {
#pragma unroll
    for (int j = 0; j < 4; ++j) {
      const int r = rt * 16 + kq * 4 + j;
      const int g = n0 + r;
      if (g < N_NODESC) {
#pragma unroll
        for (int ct = 0; ct < 4; ++ct)
          hb[(long)g * FC + col0 + ct * 16 + r16] = f2bf(acc[rt][ct][j]);
      }
      float ps = acc[rt][0][j] * asv[0] + acc[rt][1][j] * asv[1]
               + acc[rt][2][j] * asv[2] + acc[rt][3][j] * asv[3];
      float pd = acc[rt][0][j] * adv[0] + acc[rt][1][j] * adv[1]
               + acc[rt][2][j] * adv[2] + acc[rt][3][j] * adv[3];
      for (int off = 8; off; off >>= 1) {
        ps += __shfl_down(ps, off, 16);
        pd += __shfl_down(pd, off, 16);
      }
      if (r16 == 0) {
        asred[r][w] = ps;
        adred[r][w] = pd;
      }
    }
  }
  __syncthreads();
  {
    const int rr = t >> 2, hh = t & 3;
    const int g = n0 + rr;
    float mv = -INFINITY;
    if (g < N_NODESC) {
      float va = asred[rr][hh];
      as[(long)g * HEADSC + hh] = va;
      ad[(long)g * HEADSC + hh] = adred[rr][hh];
      mv = va;
    }
    // segmented max over the wave's 16 rows (same hh every 4 lanes)
    for (int off = 32; off >= 4; off >>= 1) mv = fmaxf(mv, __shfl_down(mv, off, 64));
    if (l < 4) wmax[w][l] = mv;
  }
  __syncthreads();
  if (t < 4) {
    float m = fmaxf(fmaxf(wmax[0][t], wmax[1][t]), fmaxf(wmax[2][t], wmax[3][t]));
    atomicMaxF(&asmax[t], m);
  }
}

// ----------------------------- CSR build -----------------------------------
__global__ void deg_count(const int* __restrict__ ei, int* __restrict__ deg) {
  int e = blockIdx.x * 256 + threadIdx.x;
  if (e >= E_TOTC) return;
  atomicAdd(&deg[dstOf(ei, e)], 1);
}

// 1024-thread single-block scan, 2 barriers
__global__ void scan_kernel(const int* __restrict__ deg, int* __restrict__ row_ptr,
                            int* __restrict__ cursor) {
  const int t = threadIdx.x;
  const int lane = t & 63, wid = t >> 6;           // 16 waves
  const int PER = (N_NODESC + 1023) / 1024;        // 20
  const int base = t * PER;
  int own = 0;
  for (int i = 0; i < PER; ++i) {
    int idx = base + i;
    if (idx < N_NODESC) own += deg[idx];
  }
  int inc = own;
  for (int off = 1; off < 64; off <<= 1) {
    int v = __shfl_up(inc, off, 64);
    if (lane >= off) inc += v;
  }
  __shared__ int wtot[16], woff[16];
  if (lane == 63) wtot[wid] = inc;
  __syncthreads();
  if (t == 0) {
    int r = 0;
    for (int i = 0; i < 16; ++i) { woff[i] = r; r += wtot[i]; }
  }
  __syncthreads();
  int run = woff[wid] + inc - own;
  for (int i = 0; i < PER; ++i) {
    int idx = base + i;
    if (idx < N_NODESC) {
      row_ptr[idx] = run;
      cursor[idx]  = run;
      run += deg[idx];
    }
  }
  if (t == 1023) row_ptr[N_NODESC] = run;          // = E_TOTC
}

__global__ void fill_kernel(const int* __restrict__ ei, int* __restrict__ cursor,
                            int* __restrict__ col_src) {
  int e = blockIdx.x * 256 + threadIdx.x;
  if (e >= E_TOTC) return;
  int d = dstOf(ei, e);
  int pos = atomicAdd(&cursor[d], 1);
  col_src[pos] = srcOf(ei, e);
}

// --- FUSED softmax+agg, SINGLE PASS (bound-stabilized softmax) --------------
// 1 node/block, 128 threads, thread = channel pair (2t,2t+1), head h = t>>5.
// Stabilizer m = lrelu(asmax[h] + ad[d]) >= true max -> e<=1, softmax identical.
// MODE 0: write ELU'd act as bf16 hi/lo.  MODE 1: fold gemm3 into epilogue.
template<int MODE>
__global__ void __launch_bounds__(128) fused_sa(
    const int* __restrict__ row_ptr, const int* __restrict__ col_src,
    const float* __restrict__ asf, const float4* __restrict__ ad4,
    const float* __restrict__ asmax,
    const unsigned short* __restrict__ hb, const float* __restrict__ b,
    unsigned short* __restrict__ out_hi, unsigned short* __restrict__ out_lo,
    const float* __restrict__ W3, const float* __restrict__ asc3,
    const float* __restrict__ adc3, float* __restrict__ h3,
    float* __restrict__ a3s, float* __restrict__ a3d) {
  const int d = blockIdx.x;
  const int t = threadIdx.x;                 // 0..127
  const int l = t & 63, wv = t >> 6;
  const int h = t >> 5;                      // head of channel pair
  const int j0 = row_ptr[d], j1 = row_ptr[d + 1];
  const float4 adv = ad4[d];
  const float advh = (h == 0) ? adv.x : (h == 1) ? adv.y : (h == 2) ? adv.z : adv.w;
  const float mh = lrelu(asmax[h] + advh);

  const ushort2* hb2 = (const ushort2*)hb;
  float a0 = 0.f, a1 = 0.f, sm = 0.f;
  int j = j0;
  for (; j + 8 <= j1; j += 8) {
    int     s[8];
    float   av[8];
    ushort2 v[8];
#pragma unroll
    for (int u = 0; u < 8; ++u) s[u] = col_src[j + u];
#pragma unroll
    for (int u = 0; u < 8; ++u) av[u] = asf[s[u] * 4 + h];
#pragma unroll
    for (int u = 0; u < 8; ++u) v[u] = hb2[(long)s[u] * 128 + t];
#pragma unroll
    for (int u = 0; u < 8; ++u) {
      float e = expf(lrelu(av[u] + advh) - mh);
      sm += e;
      a0 = fmaf(e, bf2f(v[u].x), a0);
      a1 = fmaf(e, bf2f(v[u].y), a1);
    }
  }
  for (; j < j1; ++j) {
    int s = col_src[j];
    float e = expf(lrelu(asf[s * 4 + h] + advh) - mh);
    ushort2 v = hb2[(long)s * 128 + t];
    sm += e;
    a0 = fmaf(e, bf2f(v.x), a0);
    a1 = fmaf(e, bf2f(v.y), a1);
  }
  const float dnh = 1.f / sm;
  float o0 = a0 * dnh + b[2 * t];
  float o1 = a1 * dnh + b[2 * t + 1];
  o0 = o0 > 0.f ? o0 : expm1f(o0);           // ELU
  o1 = o1 > 0.f ? o1 : expm1f(o1);

  if (MODE == 0) {
    ushort2 hi, lo;
    hi.x = f2bf(o0); lo.x = f2bf(o0 - bf2f(hi.x));
    hi.y = f2bf(o1); lo.y = f2bf(o1 - bf2f(hi.y));
    ((ushort2*)out_hi)[(long)d * 128 + t] = hi;
    ((ushort2*)out_lo)[(long)d * 128 + t] = lo;
  } else {
    // fused gemm3: p = o . W3 chunk; block-reduce -> h3, alphas
    float p = o0 * W3[2 * t] + o1 * W3[2 * t + 1];
    for (int off = 32; off; off >>= 1) p += __shfl_down(p, off, 64);
    __shared__ float pred[2];
    if (l == 0) pred[wv] = p;
    __syncthreads();
    if (t == 0) {
      float s = pred[0] + pred[1];
      h3[d]  = s;
      a3s[d] = s * asc3[0];
      a3d[d] = s * adc3[0];
    }
  }
}

// --- FUSED layer3 softmax+agg: out = sum(e*h3)/sum(e), wave per node -------
__global__ void __launch_bounds__(256) fused_sa3(
    const int* __restrict__ row_ptr, const int* __restrict__ col_src,
    const float* __restrict__ as, const float* __restrict__ ad,
    const float* __restrict__ h3, const float* __restrict__ b3,
    float* __restrict__ out) {
  const int wv = threadIdx.x >> 6, l = threadIdx.x & 63;
  const int d = blockIdx.x * 4 + wv;
  if (d >= N_NODESC) return;
  const int j0 = row_ptr[d], j1 = row_ptr[d + 1];
  const float adv = ad[d];
  float mx = -INFINITY;
  for (int j = j0 + l; j < j1; j += 64)
    mx = fmaxf(mx, lrelu(as[col_src[j]] + adv));
  for (int off = 32; off; off >>= 1) mx = fmaxf(mx, __shfl_xor(mx, off, 64));
  float sm = 0.f, acc = 0.f;
  for (int j = j0 + l; j < j1; j += 64) {
    int s = col_src[j];
    float e = expf(lrelu(as[s] + adv) - mx);
    sm += e;
    acc = fmaf(e, h3[s], acc);
  }
  for (int off = 32; off; off >>= 1) {
    sm  += __shfl_xor(sm, off, 64);
    acc += __shfl_xor(acc, off, 64);
  }
  if (l == 0) out[d] = acc / sm + b3[0];
}

extern "C" void kernel_launch(void* const* d_in, const int* in_sizes, int n_in,
                              void* d_out, int out_size, void* d_ws, size_t ws_size,
                              hipStream_t stream) {
  const float* x    = (const float*)d_in[0];
  const int*   ei   = (const int*)d_in[1];
  const float* W1   = (const float*)d_in[2];
  const float* as1  = (const float*)d_in[3];
  const float* ad1  = (const float*)d_in[4];
  const float* b1   = (const float*)d_in[5];
  const float* W2   = (const float*)d_in[6];
  const float* as2  = (const float*)d_in[7];
  const float* ad2  = (const float*)d_in[8];
  const float* b2   = (const float*)d_in[9];
  const float* W3   = (const float*)d_in[10];
  const float* as3  = (const float*)d_in[11];
  const float* ad3  = (const float*)d_in[12];
  const float* b3   = (const float*)d_in[13];
  float* out = (float*)d_out;

  float* ws = (float*)d_ws;
  size_t off = 0;
  float* wAs   = ws + off; off += (size_t)N_NODESC * HEADSC;
  float* wAd   = ws + off; off += (size_t)N_NODESC * HEADSC;
  float* h3    = ws + off; off += N_NODESC;
  float* a3s   = ws + off; off += N_NODESC;
  float* a3d   = ws + off; off += N_NODESC;
  float* amax  = ws + off; off += 8;                // [0..3]=layer1, [4..7]=layer2
  int* deg     = (int*)(ws + off); off += N_NODESC;
  int* row_ptr = (int*)(ws + off); off += N_NODESC + 1;
  int* cursor  = (int*)(ws + off); off += N_NODESC;
  int* col_src = (int*)(ws + off); off += E_TOTC;
  off = (off + 3) & ~(size_t)3;                     // 16B align for bf16 vectors
  unsigned short* hb     = (unsigned short*)(ws + off); off += (size_t)N_NODESC * 128;
  unsigned short* act_hi = (unsigned short*)(ws + off); off += (size_t)N_NODESC * 128;
  unsigned short* act_lo = (unsigned short*)(ws + off); off += (size_t)N_NODESC * 128;
  unsigned short* xhi    = (unsigned short*)(ws + off); off += (size_t)N_NODESC * 64;
  unsigned short* xlo    = (unsigned short*)(ws + off); off += (size_t)N_NODESC * 64;
  unsigned short* W1hiT  = (unsigned short*)(ws + off); off += 16384;   // 32768 ush
  unsigned short* W1loT  = (unsigned short*)(ws + off); off += 16384;
  unsigned short* W2hiT  = (unsigned short*)(ws + off); off += 32768;   // 65536 ush
  unsigned short* W2loT  = (unsigned short*)(ws + off); off += 32768;

  const int gridE  = (E_TOTC + 255) / 256;
  const int gridN4 = (N_NODESC + 3) / 4;
  const int gemmG  = (N_NODESC + 63) / 64;          // 313

  // ---------------- prep (1 dispatch) + CSR build --------------------------
  mega_prep<<<10463, 256, 0, stream>>>(x, xhi, xlo, W1, W1hiT, W1loT,
                                       W2, W2hiT, W2loT, deg, amax);
  deg_count<<<gridE, 256, 0, stream>>>(ei, deg);
  scan_kernel<<<1, 1024, 0, stream>>>(deg, row_ptr, cursor);
  fill_kernel<<<gridE, 256, 0, stream>>>(ei, cursor, col_src);

  // ---------------- layer 1 (K=128) ----------------
  mfma_gemm<128><<<gemmG, 256, 0, stream>>>(xhi, xlo, W1hiT, W1loT, as1, ad1,
                                            hb, wAs, wAd, amax);
  fused_sa<0><<<N_NODESC, 128, 0, stream>>>(row_ptr, col_src, wAs, (const float4*)wAd,
                                            amax, hb, b1, act_hi, act_lo,
                                            nullptr, nullptr, nullptr, nullptr, nullptr, nullptr);

  // ---------------- layer 2 (K=256), gemm3 fused into epilogue -------------
  mfma_gemm<256><<<gemmG, 256, 0, stream>>>(act_hi, act_lo, W2hiT, W2loT, as2, ad2,
                                            hb, wAs, wAd, amax + 4);
  fused_sa<1><<<N_NODESC, 128, 0, stream>>>(row_ptr, col_src, wAs, (const float4*)wAd,
                                            amax + 4, hb, b2, nullptr, nullptr,
                                            W3, as3, ad3, h3, a3s, a3d);

  // ---------------- layer 3 (heads=1, out=1) ----------------
  fused_sa3<<<gridN4, 256, 0, stream>>>(row_ptr, col_src, a3s, a3d, h3, b3, out);
}

// Round 15
// 226.305 us; speedup vs baseline: 1.3148x; 1.0203x over previous
//
#include <hip/hip_runtime.h>
#include <hip/hip_bf16.h>
#include <cmath>

#define N_NODESC 20000
#define E_RAW    320000
#define E_TOTC   340000   // + self loops
#define HEADSC   4
#define FC       256      // HEADS*HID
#define NEG_SLOPE 0.2f

typedef __attribute__((ext_vector_type(8))) short short8v;   // 8 bf16 = 4 VGPR
typedef __attribute__((ext_vector_type(4))) float f32x4;

__device__ __forceinline__ int dstOf(const int* ei, int e) {
  return (e < E_RAW) ? ei[E_RAW + e] : (e - E_RAW);
}
__device__ __forceinline__ int srcOf(const int* ei, int e) {
  return (e < E_RAW) ? ei[e] : (e - E_RAW);
}
__device__ __forceinline__ float lrelu(float v) { return v > 0.f ? v : NEG_SLOPE * v; }

__device__ __forceinline__ unsigned short f2bf(float f) {
  __hip_bfloat16 h = __float2bfloat16(f);           // RN
  return reinterpret_cast<unsigned short&>(h);
}
__device__ __forceinline__ float bf2f(unsigned short u) {
  return __uint_as_float(((unsigned int)u) << 16);
}

// Order-invariant float atomic max via int/uint monotone encoding.
__device__ __forceinline__ void atomicMaxF(float* addr, float val) {
  if (val >= 0.f) atomicMax((int*)addr, __float_as_int(val));
  else            atomicMin((unsigned int*)addr, (unsigned int)__float_as_int(val));
}

// ---- mega prep: x split + W1/W2 transpose-split + deg zero + amax init ----
__global__ void mega_prep(const float* __restrict__ x,
                          unsigned short* __restrict__ xhi, unsigned short* __restrict__ xlo,
                          const float* __restrict__ W1,
                          unsigned short* __restrict__ w1hi, unsigned short* __restrict__ w1lo,
                          const float* __restrict__ W2,
                          unsigned short* __restrict__ w2hi, unsigned short* __restrict__ w2lo,
                          int* __restrict__ deg, float* __restrict__ amax) {
  const int bid = blockIdx.x, t = threadIdx.x;
  if (bid < 10000) {                                 // x: 20000*128 = 10000 blocks exact
    int i = bid * 256 + t;
    float v = x[i];
    unsigned short hh = f2bf(v);
    xhi[i] = hh; xlo[i] = f2bf(v - bf2f(hh));
  } else if (bid < 10128) {                          // W1: 256*128 = 128 blocks
    int idx = (bid - 10000) * 256 + t;
    int c = idx >> 7, k = idx & 127;
    float v = W1[k * FC + c];
    unsigned short hh = f2bf(v);
    w1hi[c * 128 + k] = hh; w1lo[c * 128 + k] = f2bf(v - bf2f(hh));
  } else if (bid < 10384) {                          // W2: 256*256 = 256 blocks
    int idx = (bid - 10128) * 256 + t;
    int c = idx >> 8, k = idx & 255;
    float v = W2[k * FC + c];
    unsigned short hh = f2bf(v);
    w2hi[c * 256 + k] = hh; w2lo[c * 256 + k] = f2bf(v - bf2f(hh));
  } else {                                           // deg zero + amax init: 79 blocks
    int i = (bid - 10384) * 256 + t;
    if (i < N_NODESC) deg[i] = 0;
    else if (i < N_NODESC + 8) amax[i - N_NODESC] = -INFINITY;
  }
}

// ---------- MFMA GEMM + fused alpha + global-as-max (64 rows/block) --------
template<int K>
__global__ void __launch_bounds__(256) mfma_gemm(
    const unsigned short* __restrict__ Ahi, const unsigned short* __restrict__ Alo,
    const unsigned short* __restrict__ WhiT, const unsigned short* __restrict__ WloT,
    const float* __restrict__ a_src, const float* __restrict__ a_dst,
    unsigned short* __restrict__ hb, float* __restrict__ as, float* __restrict__ ad,
    float* __restrict__ asmax) {
  __shared__ float asred[64][4];
  __shared__ float adred[64][4];
  __shared__ float wmax[4][4];
  const int t = threadIdx.x;
  const int w = t >> 6, l = t & 63;
  const int n0 = blockIdx.x * 64;
  const int r16 = l & 15;
  const int kq = l >> 4;
  const int col0 = w * 64;

  f32x4 acc[4][4];
#pragma unroll
  for (int rt = 0; rt < 4; ++rt)
#pragma unroll
    for (int ct = 0; ct < 4; ++ct) acc[rt][ct] = f32x4{0.f, 0.f, 0.f, 0.f};

  long arow[4];
#pragma unroll
  for (int rt = 0; rt < 4; ++rt) {
    int r = n0 + rt * 16 + r16;
    if (r >= N_NODESC) r = N_NODESC - 1;
    arow[rt] = (long)r * K;
  }

  for (int ks = 0; ks < K; ks += 32) {
    const int kb = ks + kq * 8;
    short8v aHi[4], aLo[4];
#pragma unroll
    for (int rt = 0; rt < 4; ++rt) {
      aHi[rt] = *(const short8v*)(Ahi + arow[rt] + kb);
      aLo[rt] = *(const short8v*)(Alo + arow[rt] + kb);
    }
#pragma unroll
    for (int ct = 0; ct < 4; ++ct) {
      const long wrow = (long)(col0 + ct * 16 + r16) * K + kb;
      short8v wHi = *(const short8v*)(WhiT + wrow);
      short8v wLo = *(const short8v*)(WloT + wrow);
#pragma unroll
      for (int rt = 0; rt < 4; ++rt) {
        acc[rt][ct] = __builtin_amdgcn_mfma_f32_16x16x32_bf16(aHi[rt], wHi, acc[rt][ct], 0, 0, 0);
        acc[rt][ct] = __builtin_amdgcn_mfma_f32_16x16x32_bf16(aHi[rt], wLo, acc[rt][ct], 0, 0, 0);
        acc[rt][ct] = __builtin_amdgcn_mfma_f32_16x16x32_bf16(aLo[rt], wHi, acc[rt][ct], 0, 0, 0);
      }
    }
  }

  float asv[4], adv[4];
#pragma unroll
  for (int ct = 0; ct < 4; ++ct) {
    int c = col0 + ct * 16 + r16;
    asv[ct] = a_src[c];
    adv[ct] = a_dst[c];
  }
#pragma unroll
  for (int rt = 0; rt < 4; ++rt) {
#pragma unroll
    for (int j = 0; j < 4; ++j) {
      const int r = rt * 16 + kq * 4 + j;
      const int g = n0 + r;
      if (g < N_NODESC) {
#pragma unroll
        for (int ct = 0; ct < 4; ++ct)
          hb[(long)g * FC + col0 + ct * 16 + r16] = f2bf(acc[rt][ct][j]);
      }
      float ps = acc[rt][0][j] * asv[0] + acc[rt][1][j] * asv[1]
               + acc[rt][2][j] * asv[2] + acc[rt][3][j] * asv[3];
      float pd = acc[rt][0][j] * adv[0] + acc[rt][1][j] * adv[1]
               + acc[rt][2][j] * adv[2] + acc[rt][3][j] * adv[3];
      for (int off = 8; off; off >>= 1) {
        ps += __shfl_down(ps, off, 16);
        pd += __shfl_down(pd, off, 16);
      }
      if (r16 == 0) {
        asred[r][w] = ps;
        adred[r][w] = pd;
      }
    }
  }
  __syncthreads();
  {
    const int rr = t >> 2, hh = t & 3;
    const int g = n0 + rr;
    float mv = -INFINITY;
    if (g < N_NODESC) {
      float va = asred[rr][hh];
      as[(long)g * HEADSC + hh] = va;
      ad[(long)g * HEADSC + hh] = adred[rr][hh];
      mv = va;
    }
    for (int off = 32; off >= 4; off >>= 1) mv = fmaxf(mv, __shfl_down(mv, off, 64));
    if (l < 4) wmax[w][l] = mv;
  }
  __syncthreads();
  if (t < 4) {
    float m = fmaxf(fmaxf(wmax[0][t], wmax[1][t]), fmaxf(wmax[2][t], wmax[3][t]));
    atomicMaxF(&asmax[t], m);
  }
}

// ----------------------------- CSR build -----------------------------------
__global__ void deg_count(const int* __restrict__ ei, int* __restrict__ deg) {
  int e = blockIdx.x * 256 + threadIdx.x;
  if (e >= E_TOTC) return;
  atomicAdd(&deg[dstOf(ei, e)], 1);
}

// 1024-thread single-block scan, 2 barriers
__global__ void scan_kernel(const int* __restrict__ deg, int* __restrict__ row_ptr,
                            int* __restrict__ cursor) {
  const int t = threadIdx.x;
  const int lane = t & 63, wid = t >> 6;           // 16 waves
  const int PER = (N_NODESC + 1023) / 1024;        // 20
  const int base = t * PER;
  int own = 0;
  for (int i = 0; i < PER; ++i) {
    int idx = base + i;
    if (idx < N_NODESC) own += deg[idx];
  }
  int inc = own;
  for (int off = 1; off < 64; off <<= 1) {
    int v = __shfl_up(inc, off, 64);
    if (lane >= off) inc += v;
  }
  __shared__ int wtot[16], woff[16];
  if (lane == 63) wtot[wid] = inc;
  __syncthreads();
  if (t == 0) {
    int r = 0;
    for (int i = 0; i < 16; ++i) { woff[i] = r; r += wtot[i]; }
  }
  __syncthreads();
  int run = woff[wid] + inc - own;
  for (int i = 0; i < PER; ++i) {
    int idx = base + i;
    if (idx < N_NODESC) {
      row_ptr[idx] = run;
      cursor[idx]  = run;
      run += deg[idx];
    }
  }
  if (t == 1023) row_ptr[N_NODESC] = run;          // = E_TOTC
}

__global__ void fill_kernel(const int* __restrict__ ei, int* __restrict__ cursor,
                            int* __restrict__ col_src) {
  int e = blockIdx.x * 256 + threadIdx.x;
  if (e >= E_TOTC) return;
  int d = dstOf(ei, e);
  int pos = atomicAdd(&cursor[d], 1);
  col_src[pos] = srcOf(ei, e);
}

// --- FUSED softmax+agg, WAVE PER NODE (bound-stabilized, single pass) -------
// 256 threads = 4 waves = 4 nodes/block. Lane owns 4 channels (ushort4 = 8B).
// head h = lane>>4. No barriers, no LDS (MODE 0); wave-reduce only (MODE 1).
template<int MODE>
__global__ void __launch_bounds__(256) fused_sa(
    const int* __restrict__ row_ptr, const int* __restrict__ col_src,
    const float* __restrict__ asf, const float4* __restrict__ ad4,
    const float* __restrict__ asmax,
    const unsigned short* __restrict__ hb, const float* __restrict__ b,
    unsigned short* __restrict__ out_hi, unsigned short* __restrict__ out_lo,
    const float* __restrict__ W3, const float* __restrict__ asc3,
    const float* __restrict__ adc3, float* __restrict__ h3,
    float* __restrict__ a3s, float* __restrict__ a3d) {
  const int l = threadIdx.x & 63, wv = threadIdx.x >> 6;
  const int d = blockIdx.x * 4 + wv;                // 5000*4 = 20000 exact
  const int h = l >> 4;                             // head of 4-channel group
  const int j0 = row_ptr[d], j1 = row_ptr[d + 1];
  const float4 adv = ad4[d];
  const float advh = (h == 0) ? adv.x : (h == 1) ? adv.y : (h == 2) ? adv.z : adv.w;
  const float mh = lrelu(asmax[h] + advh);

  const ushort4* hb4 = (const ushort4*)hb;          // 64 quads per row
  float a0 = 0.f, a1 = 0.f, a2 = 0.f, a3 = 0.f, sm = 0.f;
  int j = j0;
  for (; j + 8 <= j1; j += 8) {
    int     s[8];
    float   av[8];
    ushort4 v[8];
#pragma unroll
    for (int u = 0; u < 8; ++u) s[u] = col_src[j + u];
#pragma unroll
    for (int u = 0; u < 8; ++u) av[u] = asf[s[u] * 4 + h];
#pragma unroll
    for (int u = 0; u < 8; ++u) v[u] = hb4[(long)s[u] * 64 + l];
#pragma unroll
    for (int u = 0; u < 8; ++u) {
      float e = expf(lrelu(av[u] + advh) - mh);
      sm += e;
      a0 = fmaf(e, bf2f(v[u].x), a0);
      a1 = fmaf(e, bf2f(v[u].y), a1);
      a2 = fmaf(e, bf2f(v[u].z), a2);
      a3 = fmaf(e, bf2f(v[u].w), a3);
    }
  }
  for (; j < j1; ++j) {
    int s = col_src[j];
    float e = expf(lrelu(asf[s * 4 + h] + advh) - mh);
    ushort4 v = hb4[(long)s * 64 + l];
    sm += e;
    a0 = fmaf(e, bf2f(v.x), a0);
    a1 = fmaf(e, bf2f(v.y), a1);
    a2 = fmaf(e, bf2f(v.z), a2);
    a3 = fmaf(e, bf2f(v.w), a3);
  }
  const float dn = 1.f / sm;
  float4 bb = *(const float4*)(b + 4 * l);
  float o0 = a0 * dn + bb.x;
  float o1 = a1 * dn + bb.y;
  float o2 = a2 * dn + bb.z;
  float o3 = a3 * dn + bb.w;
  o0 = o0 > 0.f ? o0 : expm1f(o0);                  // ELU
  o1 = o1 > 0.f ? o1 : expm1f(o1);
  o2 = o2 > 0.f ? o2 : expm1f(o2);
  o3 = o3 > 0.f ? o3 : expm1f(o3);

  if (MODE == 0) {
    ushort4 hi, lo;
    hi.x = f2bf(o0); lo.x = f2bf(o0 - bf2f(hi.x));
    hi.y = f2bf(o1); lo.y = f2bf(o1 - bf2f(hi.y));
    hi.z = f2bf(o2); lo.z = f2bf(o2 - bf2f(hi.z));
    hi.w = f2bf(o3); lo.w = f2bf(o3 - bf2f(hi.w));
    ((ushort4*)out_hi)[(long)d * 64 + l] = hi;
    ((ushort4*)out_lo)[(long)d * 64 + l] = lo;
  } else {
    // fused gemm3: p = o . W3 chunk; wave-reduce -> h3, alphas
    float4 w3 = *(const float4*)(W3 + 4 * l);
    float p = o0 * w3.x + o1 * w3.y + o2 * w3.z + o3 * w3.w;
    for (int off = 32; off; off >>= 1) p += __shfl_down(p, off, 64);
    if (l == 0) {
      h3[d]  = p;
      a3s[d] = p * asc3[0];
      a3d[d] = p * adc3[0];
    }
  }
}

// --- FUSED layer3 softmax+agg: out = sum(e*h3)/sum(e), wave per node -------
__global__ void __launch_bounds__(256) fused_sa3(
    const int* __restrict__ row_ptr, const int* __restrict__ col_src,
    const float* __restrict__ as, const float* __restrict__ ad,
    const float* __restrict__ h3, const float* __restrict__ b3,
    float* __restrict__ out) {
  const int wv = threadIdx.x >> 6, l = threadIdx.x & 63;
  const int d = blockIdx.x * 4 + wv;
  if (d >= N_NODESC) return;
  const int j0 = row_ptr[d], j1 = row_ptr[d + 1];
  const float adv = ad[d];
  float mx = -INFINITY;
  for (int j = j0 + l; j < j1; j += 64)
    mx = fmaxf(mx, lrelu(as[col_src[j]] + adv));
  for (int off = 32; off; off >>= 1) mx = fmaxf(mx, __shfl_xor(mx, off, 64));
  float sm = 0.f, acc = 0.f;
  for (int j = j0 + l; j < j1; j += 64) {
    int s = col_src[j];
    float e = expf(lrelu(as[s] + adv) - mx);
    sm += e;
    acc = fmaf(e, h3[s], acc);
  }
  for (int off = 32; off; off >>= 1) {
    sm  += __shfl_xor(sm, off, 64);
    acc += __shfl_xor(acc, off, 64);
  }
  if (l == 0) out[d] = acc / sm + b3[0];
}

extern "C" void kernel_launch(void* const* d_in, const int* in_sizes, int n_in,
                              void* d_out, int out_size, void* d_ws, size_t ws_size,
                              hipStream_t stream) {
  const float* x    = (const float*)d_in[0];
  const int*   ei   = (const int*)d_in[1];
  const float* W1   = (const float*)d_in[2];
  const float* as1  = (const float*)d_in[3];
  const float* ad1  = (const float*)d_in[4];
  const float* b1   = (const float*)d_in[5];
  const float* W2   = (const float*)d_in[6];
  const float* as2  = (const float*)d_in[7];
  const float* ad2  = (const float*)d_in[8];
  const float* b2   = (const float*)d_in[9];
  const float* W3   = (const float*)d_in[10];
  const float* as3  = (const float*)d_in[11];
  const float* ad3  = (const float*)d_in[12];
  const float* b3   = (const float*)d_in[13];
  float* out = (float*)d_out;

  float* ws = (float*)d_ws;
  size_t off = 0;
  float* wAs   = ws + off; off += (size_t)N_NODESC * HEADSC;
  float* wAd   = ws + off; off += (size_t)N_NODESC * HEADSC;
  float* h3    = ws + off; off += N_NODESC;
  float* a3s   = ws + off; off += N_NODESC;
  float* a3d   = ws + off; off += N_NODESC;
  float* amax  = ws + off; off += 8;                // [0..3]=layer1, [4..7]=layer2
  int* deg     = (int*)(ws + off); off += N_NODESC;
  int* row_ptr = (int*)(ws + off); off += N_NODESC + 1;
  int* cursor  = (int*)(ws + off); off += N_NODESC;
  int* col_src = (int*)(ws + off); off += E_TOTC;
  off = (off + 3) & ~(size_t)3;                     // 16B align for bf16 vectors
  unsigned short* hb     = (unsigned short*)(ws + off); off += (size_t)N_NODESC * 128;
  unsigned short* act_hi = (unsigned short*)(ws + off); off += (size_t)N_NODESC * 128;
  unsigned short* act_lo = (unsigned short*)(ws + off); off += (size_t)N_NODESC * 128;
  unsigned short* xhi    = (unsigned short*)(ws + off); off += (size_t)N_NODESC * 64;
  unsigned short* xlo    = (unsigned short*)(ws + off); off += (size_t)N_NODESC * 64;
  unsigned short* W1hiT  = (unsigned short*)(ws + off); off += 16384;   // 32768 ush
  unsigned short* W1loT  = (unsigned short*)(ws + off); off += 16384;
  unsigned short* W2hiT  = (unsigned short*)(ws + off); off += 32768;   // 65536 ush
  unsigned short* W2loT  = (unsigned short*)(ws + off); off += 32768;

  const int gridE  = (E_TOTC + 255) / 256;
  const int gridN4 = (N_NODESC + 3) / 4;
  const int gemmG  = (N_NODESC + 63) / 64;          // 313

  // ---------------- prep (1 dispatch) + CSR build --------------------------
  mega_prep<<<10463, 256, 0, stream>>>(x, xhi, xlo, W1, W1hiT, W1loT,
                                       W2, W2hiT, W2loT, deg, amax);
  deg_count<<<gridE, 256, 0, stream>>>(ei, deg);
  scan_kernel<<<1, 1024, 0, stream>>>(deg, row_ptr, cursor);
  fill_kernel<<<gridE, 256, 0, stream>>>(ei, cursor, col_src);

  // ---------------- layer 1 (K=128) ----------------
  mfma_gemm<128><<<gemmG, 256, 0, stream>>>(xhi, xlo, W1hiT, W1loT, as1, ad1,
                                            hb, wAs, wAd, amax);
  fused_sa<0><<<N_NODESC / 4, 256, 0, stream>>>(row_ptr, col_src, wAs, (const float4*)wAd,
                                                amax, hb, b1, act_hi, act_lo,
                                                nullptr, nullptr, nullptr, nullptr, nullptr, nullptr);

  // ---------------- layer 2 (K=256), gemm3 fused into epilogue -------------
  mfma_gemm<256><<<gemmG, 256, 0, stream>>>(act_hi, act_lo, W2hiT, W2loT, as2, ad2,
                                            hb, wAs, wAd, amax + 4);
  fused_sa<1><<<N_NODESC / 4, 256, 0, stream>>>(row_ptr, col_src, wAs, (const float4*)wAd,
                                                amax + 4, hb, b2, nullptr, nullptr,
                                                W3, as3, ad3, h3, a3s, a3d);

  // ---------------- layer 3 (heads=1, out=1) ----------------
  fused_sa3<<<gridN4, 256, 0, stream>>>(row_ptr, col_src, a3s, a3d, h3, b3, out);
}